// Round 19
// baseline (1189.266 us; speedup 1.0000x reference)
//
#include <hip/hip_runtime.h>
#include <hip/hip_bf16.h>

#define NMESH 50000
#define GRIDN 32768
#define NEDGE 131072
#define HID 384

using f32x4 = __attribute__((ext_vector_type(4))) float;
using bfrag = __attribute__((ext_vector_type(8))) short;
using i32x4 = __attribute__((ext_vector_type(4))) int;

__device__ __forceinline__ float gelu_f(float v) {
    return 0.5f * v * (1.0f + erff(v * 0.70710678118654752f));
}

__device__ __forceinline__ void load_lds16(const void* g, void* l) {
    __builtin_amdgcn_global_load_lds(
        (const __attribute__((address_space(1))) void*)g,
        (__attribute__((address_space(3))) void*)l,
        16, 0, 0);
}

// bijective XCD-chunking swizzle (m204)
__device__ __forceinline__ void xcd_swizzle(int& bx, int& by) {
    int gx = gridDim.x;
    int nwg = gx * gridDim.y;
    int l = blockIdx.y * gx + blockIdx.x;
    int q = nwg >> 3, r = nwg & 7;
    int xcd = l & 7, pos = l >> 3;
    int nl = (xcd < r ? xcd * (q + 1) : r * (q + 1) + (xcd - r) * q) + pos;
    by = nl / gx;
    bx = nl - by * gx;
}

// unpack 8+8 bf16, add f32, gelu, repack
__device__ __forceinline__ bfrag fuse8(i32x4 u, i32x4 v) {
    bfrag ub = *reinterpret_cast<bfrag*>(&u);
    bfrag vb = *reinterpret_cast<bfrag*>(&v);
    bfrag o;
    #pragma unroll
    for (int i = 0; i < 8; i++) {
        unsigned short us = (unsigned short)ub[i], vs = (unsigned short)vb[i];
        float a = __bfloat162float(*(__hip_bfloat16*)&us) + __bfloat162float(*(__hip_bfloat16*)&vs);
        a = gelu_f(a);
        __hip_bfloat16 hb = __float2bfloat16(a);
        o[i] = *(short*)&hb;
    }
    return o;
}

// ---------------- weight transpose + bf16 cast: wt[n*K+k] = w[(k0+k)*N+n] ----------------
__global__ void transpose_to_bf16(const float* __restrict__ w, __hip_bfloat16* __restrict__ wt,
                                  int K, int N, int k0) {
    int idx = blockIdx.x * blockDim.x + threadIdx.x;
    if (idx >= K * N) return;
    int n = idx / K;
    int k = idx - n * K;
    wt[idx] = __float2bfloat16(w[(size_t)(k0 + k) * N + n]);
}

// ---------------- fold w3 into wm1 ----------------
__global__ void fold_w3_wm1(const float* __restrict__ w3, const float* __restrict__ wm1,
                            __hip_bfloat16* __restrict__ wtf) {
    int idx = blockIdx.x * blockDim.x + threadIdx.x;
    if (idx >= 576 * 768) return;
    int k = idx / 768;
    int n = idx - k * 768;
    float acc;
    if (k < 384) {
        acc = 0.f;
        #pragma unroll 4
        for (int j = 0; j < 384; j++)
            acc = fmaf(w3[k * 384 + j], wm1[j * 768 + n], acc);
    } else {
        acc = wm1[(size_t)k * 768 + n];
    }
    wtf[(size_t)n * 576 + k] = __float2bfloat16(acc);
}

// ---------------- folded bias ----------------
__global__ void fold_bias(const float* __restrict__ b3, const float* __restrict__ wm1,
                          const float* __restrict__ bm1, float* __restrict__ bf) {
    int n = blockIdx.x * blockDim.x + threadIdx.x;
    if (n >= 768) return;
    float acc = bm1[n];
    #pragma unroll 4
    for (int k = 0; k < 384; k++) acc = fmaf(b3[k], wm1[(size_t)k * 768 + n], acc);
    bf[n] = acc;
}

// ---------------- rowstart[g] = lower_bound(edges[:,0], g) ----------------
__global__ void calc_rowstart(const int* __restrict__ edges, int* __restrict__ rs) {
    int g = blockIdx.x * blockDim.x + threadIdx.x;
    if (g > GRIDN) return;
    int l = 0, r = NEDGE;
    while (l < r) { int m = (l + r) >> 1; if (edges[2 * m] < g) l = m + 1; else r = m; }
    rs[g] = l;
}

// ---------------- sincos positional embedding ----------------
__global__ void embed_kernel(const float* __restrict__ pos, __hip_bfloat16* __restrict__ outp,
                             int n, int stride, int coloff) {
    int idx = blockIdx.x * blockDim.x + threadIdx.x;
    if (idx >= n * 96) return;
    int nn = idx / 96;
    int rr = idx - nn * 96;
    int d = rr >> 5;
    int k = rr & 31;
    float v = pos[nn * 3 + d];
    float omega = expf(-0.28782313662425575f * (float)k);  // ln(10000)/32
    float a = v * omega;
    __hip_bfloat16* o = outp + (size_t)nn * stride + coloff + d * 64 + k;
    o[0]  = __float2bfloat16(sinf(a));
    o[32] = __float2bfloat16(cosf(a));
}

// ---------------- layer 1 ----------------
__global__ void lin1_kernel(const float* __restrict__ x, const float* __restrict__ w,
                            const float* __restrict__ b, __hip_bfloat16* __restrict__ h1) {
    int idx = blockIdx.x * blockDim.x + threadIdx.x;
    if (idx >= NMESH * HID) return;
    int m = idx / HID;
    int n = idx - m * HID;
    float acc = b[n];
    const float* xr = x + m * 16;
    #pragma unroll
    for (int k = 0; k < 16; k++) acc = fmaf(xr[k], w[k * HID + n], acc);
    h1[idx] = __float2bfloat16(gelu_f(acc));
}

// ======================================================================
// 128x128-tile bf16 MFMA GEMM (proven body; N=384 shapes + fallback).
// ======================================================================
template<bool GELU, bool F32OUT, bool SEGA>
__launch_bounds__(256, 3)
__global__ void mfma_gemm(const __hip_bfloat16* __restrict__ A,
                          const __hip_bfloat16* __restrict__ Wt,
                          const float* __restrict__ bias,
                          void* __restrict__ Cv, void* __restrict__ Cv2,
                          int M, int N, int K, int ldc,
                          const int* __restrict__ seg_edges, int seg_e0) {
    __shared__ __align__(16) __hip_bfloat16 As[3][4096];
    __shared__ __align__(16) __hip_bfloat16 Bs[3][4096];

    const int t = threadIdx.x;
    const int lane = t & 63;
    const int wave = t >> 6;
    const int wm0 = (wave >> 1) * 64;
    const int wn0 = (wave & 1) * 64;

    int bx, by;
    xcd_swizzle(bx, by);
    const int row0 = by * 128;
    const int col0 = bx * 128;

    const int rS0 = t >> 2;
    const int rS1 = rS0 + 64;
    const int kcS = (t & 3) ^ ((t >> 3) & 3);

    const __hip_bfloat16* aP0 = A + (size_t)min(row0 + rS0, M - 1) * K;
    const __hip_bfloat16* aP1 = A + (size_t)min(row0 + rS1, M - 1) * K;
    const __hip_bfloat16* bP0 = Wt + (size_t)(col0 + rS0) * K;
    const __hip_bfloat16* bP1 = Wt + (size_t)(col0 + rS1) * K;

    const int off0 = (wave * 64) * 16;
    const int off1 = (256 + wave * 64) * 16;

    f32x4 acc[4][4] = {};

    const int kq = lane >> 4;
    const int lr = lane & 15;
    const int kqx = kq ^ ((lr >> 1) & 3);
    const int rdA = (wm0 + lr) * 32 + kqx * 8;
    const int rdB = (wn0 + lr) * 32 + kqx * 8;

    const int nsteps = K >> 5;

    auto stage = [&](int ks, int buf) {
        int k = ks * 32 + kcS * 8;
        load_lds16(aP0 + k, (char*)As[buf] + off0);
        load_lds16(aP1 + k, (char*)As[buf] + off1);
        load_lds16(bP0 + k, (char*)Bs[buf] + off0);
        load_lds16(bP1 + k, (char*)Bs[buf] + off1);
    };

    stage(0, 0);
    stage(1, 1);

    int cur = 0;
    int stg = 2;
    for (int ks = 0; ks < nsteps; ks++) {
        if (ks + 1 < nsteps) {
            asm volatile("s_waitcnt vmcnt(4)" ::: "memory");
        } else {
            asm volatile("s_waitcnt vmcnt(0)" ::: "memory");
        }
        __builtin_amdgcn_s_barrier();
        if (ks + 2 < nsteps) stage(ks + 2, stg);

        bfrag aF[4], bF[4];
        #pragma unroll
        for (int i = 0; i < 4; i++) {
            aF[i] = *reinterpret_cast<const bfrag*>(&As[cur][rdA + i * 512]);
            bF[i] = *reinterpret_cast<const bfrag*>(&Bs[cur][rdB + i * 512]);
        }
        asm volatile("s_waitcnt lgkmcnt(0)" ::: "memory");
        __builtin_amdgcn_sched_barrier(0);
        __builtin_amdgcn_s_setprio(1);
        #pragma unroll
        for (int i = 0; i < 4; i++) {
            #pragma unroll
            for (int j = 0; j < 4; j++) {
                acc[i][j] = __builtin_amdgcn_mfma_f32_16x16x32_bf16(aF[i], bF[j], acc[i][j], 0, 0, 0);
            }
        }
        __builtin_amdgcn_s_setprio(0);

        cur = (cur == 2) ? 0 : cur + 1;
        stg = (stg == 2) ? 0 : stg + 1;
    }

    if constexpr (SEGA) {
        float* o0 = (float*)Cv;
        float* o1 = (float*)Cv2;
        #pragma unroll
        for (int i = 0; i < 4; i++) {
            int rbase = seg_e0 + row0 + wm0 + i * 16 + kq * 4;
            int g0 = seg_edges[2 * (rbase + 0)];
            int g1 = seg_edges[2 * (rbase + 1)];
            int g2 = seg_edges[2 * (rbase + 2)];
            int g3 = seg_edges[2 * (rbase + 3)];
            bool same = (g0 == g1) & (g1 == g2) & (g2 == g3);
            #pragma unroll
            for (int j = 0; j < 4; j++) {
                int col = col0 + wn0 + j * 16 + lr;
                float* base = (col < 384) ? (o0 + col) : (o1 + (col - 384));
                float v0 = gelu_f(acc[i][j][0] + bias[col]);
                float v1 = gelu_f(acc[i][j][1] + bias[col]);
                float v2 = gelu_f(acc[i][j][2] + bias[col]);
                float v3 = gelu_f(acc[i][j][3] + bias[col]);
                if (same) {
                    unsafeAtomicAdd(base + (size_t)g0 * 384, v0 + v1 + v2 + v3);
                } else {
                    unsafeAtomicAdd(base + (size_t)g0 * 384, v0);
                    unsafeAtomicAdd(base + (size_t)g1 * 384, v1);
                    unsafeAtomicAdd(base + (size_t)g2 * 384, v2);
                    unsafeAtomicAdd(base + (size_t)g3 * 384, v3);
                }
            }
        }
    } else {
        #pragma unroll
        for (int i = 0; i < 4; i++) {
            #pragma unroll
            for (int j = 0; j < 4; j++) {
                #pragma unroll
                for (int r = 0; r < 4; r++) {
                    int row = row0 + wm0 + i * 16 + kq * 4 + r;
                    int col = col0 + wn0 + j * 16 + lr;
                    if (row < M) {
                        float v = acc[i][j][r] + bias[col];
                        if constexpr (GELU) v = gelu_f(v);
                        if constexpr (F32OUT)
                            ((float*)Cv)[(size_t)row * ldc + col] = v;
                        else
                            ((__hip_bfloat16*)Cv)[(size_t)row * ldc + col] = __float2bfloat16(v);
                    }
                }
            }
        }
    }
}

// ======================================================================
// 256x256-tile bf16 MFMA GEMM, BK=32, 512 threads, 8 waves (2Mx4N),
// per-wave 128x64 out -> 32 MFMA/wave/step (2x the 128^2 kernel's
// per-step matrix work at the same staging+barrier cost). 3-buffer
// counted-vmcnt pipeline with IDENTICAL schedule constants (vmcnt(4)
// retires tile ks; tile ks+1 stays in flight ACROSS the raw barrier --
// no r8-style per-step drain, so 1 block/CU stays fed). Same proven
// source-pre-swizzle + kqx fragment reads (slot p = (row=p>>2,
// kc=(p&3)^((p>>3)&3)); involution verified, 0-conflict geometry).
// VGPR ~200 < 256 cap of (512,2). LDS 96KB -> 1 block/CU.
// ======================================================================
template<bool GELU, bool SEGA>
__launch_bounds__(512, 2)
__global__ void mfma_gemm256(const __hip_bfloat16* __restrict__ A,
                             const __hip_bfloat16* __restrict__ Wt,
                             const float* __restrict__ bias,
                             void* __restrict__ Cv, void* __restrict__ Cv2,
                             int M, int N, int K, int ldc,
                             const int* __restrict__ seg_edges, int seg_e0) {
    __shared__ __align__(16) __hip_bfloat16 As[3][8192];  // 256 rows x 32 k
    __shared__ __align__(16) __hip_bfloat16 Bs[3][8192];

    const int t = threadIdx.x;       // 0..511
    const int lane = t & 63;
    const int wave = t >> 6;         // 0..7
    const int wm0 = (wave >> 2) * 128;
    const int wn0 = (wave & 3) * 64;

    int bx, by;
    xcd_swizzle(bx, by);
    const int row0 = by * 256;
    const int col0 = bx * 256;

    const int rS0 = t >> 2;          // rows 0..127
    const int rS1 = rS0 + 128;       // rows 128..255
    const int kcS = (t & 3) ^ ((t >> 3) & 3);

    const __hip_bfloat16* aP0 = A + (size_t)min(row0 + rS0, M - 1) * K;
    const __hip_bfloat16* aP1 = A + (size_t)min(row0 + rS1, M - 1) * K;
    const __hip_bfloat16* bP0 = Wt + (size_t)(col0 + rS0) * K;
    const __hip_bfloat16* bP1 = Wt + (size_t)(col0 + rS1) * K;

    const int off0 = (wave * 64) * 16;           // slots t
    const int off1 = (512 + wave * 64) * 16;     // slots t+512

    f32x4 acc[8][4] = {};

    const int kq = lane >> 4;
    const int lr = lane & 15;
    const int kqx = kq ^ ((lr >> 1) & 3);
    const int rdA = (wm0 + lr) * 32 + kqx * 8;   // frag i at + i*512
    const int rdB = (wn0 + lr) * 32 + kqx * 8;   // frag j at + j*512

    const int nsteps = K >> 5;

    auto stage = [&](int ks, int buf) {
        int k = ks * 32 + kcS * 8;
        load_lds16(aP0 + k, (char*)As[buf] + off0);
        load_lds16(aP1 + k, (char*)As[buf] + off1);
        load_lds16(bP0 + k, (char*)Bs[buf] + off0);
        load_lds16(bP1 + k, (char*)Bs[buf] + off1);
    };

    stage(0, 0);
    stage(1, 1);

    int cur = 0;
    int stg = 2;
    for (int ks = 0; ks < nsteps; ks++) {
        if (ks + 1 < nsteps) {
            asm volatile("s_waitcnt vmcnt(4)" ::: "memory");
        } else {
            asm volatile("s_waitcnt vmcnt(0)" ::: "memory");
        }
        __builtin_amdgcn_s_barrier();
        if (ks + 2 < nsteps) stage(ks + 2, stg);

        bfrag aF[8], bF[4];
        #pragma unroll
        for (int i = 0; i < 8; i++)
            aF[i] = *reinterpret_cast<const bfrag*>(&As[cur][rdA + i * 512]);
        #pragma unroll
        for (int j = 0; j < 4; j++)
            bF[j] = *reinterpret_cast<const bfrag*>(&Bs[cur][rdB + j * 512]);
        asm volatile("s_waitcnt lgkmcnt(0)" ::: "memory");
        __builtin_amdgcn_sched_barrier(0);
        __builtin_amdgcn_s_setprio(1);
        #pragma unroll
        for (int i = 0; i < 8; i++) {
            #pragma unroll
            for (int j = 0; j < 4; j++) {
                acc[i][j] = __builtin_amdgcn_mfma_f32_16x16x32_bf16(aF[i], bF[j], acc[i][j], 0, 0, 0);
            }
        }
        __builtin_amdgcn_s_setprio(0);

        cur = (cur == 2) ? 0 : cur + 1;
        stg = (stg == 2) ? 0 : stg + 1;
    }

    if constexpr (SEGA) {
        float* o0 = (float*)Cv;    // cols [0,384), stride 384
        float* o1 = (float*)Cv2;   // cols [384,768), stride 384
        #pragma unroll
        for (int i = 0; i < 8; i++) {
            int rbase = seg_e0 + row0 + wm0 + i * 16 + kq * 4;
            int g0 = seg_edges[2 * (rbase + 0)];
            int g1 = seg_edges[2 * (rbase + 1)];
            int g2 = seg_edges[2 * (rbase + 2)];
            int g3 = seg_edges[2 * (rbase + 3)];
            bool same = (g0 == g1) & (g1 == g2) & (g2 == g3);
            #pragma unroll
            for (int j = 0; j < 4; j++) {
                int col = col0 + wn0 + j * 16 + lr;
                float* base = (col < 384) ? (o0 + col) : (o1 + (col - 384));
                float v0 = gelu_f(acc[i][j][0] + bias[col]);
                float v1 = gelu_f(acc[i][j][1] + bias[col]);
                float v2 = gelu_f(acc[i][j][2] + bias[col]);
                float v3 = gelu_f(acc[i][j][3] + bias[col]);
                if (same) {
                    unsafeAtomicAdd(base + (size_t)g0 * 384, v0 + v1 + v2 + v3);
                } else {
                    unsafeAtomicAdd(base + (size_t)g0 * 384, v0);
                    unsafeAtomicAdd(base + (size_t)g1 * 384, v1);
                    unsafeAtomicAdd(base + (size_t)g2 * 384, v2);
                    unsafeAtomicAdd(base + (size_t)g3 * 384, v3);
                }
            }
        }
    } else {
        #pragma unroll
        for (int i = 0; i < 8; i++) {
            #pragma unroll
            for (int j = 0; j < 4; j++) {
                #pragma unroll
                for (int r = 0; r < 4; r++) {
                    int row = row0 + wm0 + i * 16 + kq * 4 + r;
                    int col = col0 + wn0 + j * 16 + lr;
                    if (row < M) {
                        float v = acc[i][j][r] + bias[col];
                        if constexpr (GELU) v = gelu_f(v);
                        ((__hip_bfloat16*)Cv)[(size_t)row * ldc + col] = __float2bfloat16(v);
                    }
                }
            }
        }
    }
}

// ---------------- m1 fuse: m1c[e] = gelu(U[mesh_idx[e]] + V[grid_idx[e]]) ----------------
__global__ void fuse_m1(const __hip_bfloat16* __restrict__ U, const __hip_bfloat16* __restrict__ V,
                        const int* __restrict__ edges, int e0, int ne,
                        __hip_bfloat16* __restrict__ m1c) {
    int idx = blockIdx.x * blockDim.x + threadIdx.x;
    if (idx >= ne * 96) return;
    int e = idx / 96;
    int c8 = (idx - e * 96) * 8;
    int ge = e0 + e;
    int mi = edges[2 * ge + 1];
    int gi = edges[2 * ge + 0];
    i32x4 u = *reinterpret_cast<const i32x4*>(U + (size_t)mi * 768 + c8);
    i32x4 v = *reinterpret_cast<const i32x4*>(V + (size_t)gi * 768 + c8);
    *reinterpret_cast<bfrag*>(m1c + (size_t)e * 768 + c8) = fuse8(u, v);
}

// ---------------- meanM2 = bf16(split_sums / max(cnt,1)) ----------------
__global__ void mean_bf16(const float* __restrict__ s0, const float* __restrict__ s1,
                          const int* __restrict__ rs, __hip_bfloat16* __restrict__ mm) {
    int idx = blockIdx.x * blockDim.x + threadIdx.x;
    int base = idx * 4;
    if (base >= GRIDN * 768) return;
    int g = base / 768;
    int c = base - g * 768;
    int cnt = rs[g + 1] - rs[g];
    float inv = 1.0f / (float)max(cnt, 1);
    float4 v = (c < 384) ? *reinterpret_cast<const float4*>(s0 + (size_t)g * 384 + c)
                         : *reinterpret_cast<const float4*>(s1 + (size_t)g * 384 + (c - 384));
    __hip_bfloat16 o[4] = {__float2bfloat16(v.x * inv), __float2bfloat16(v.y * inv),
                           __float2bfloat16(v.z * inv), __float2bfloat16(v.w * inv)};
    *reinterpret_cast<uint2*>(mm + base) = *reinterpret_cast<const uint2*>(o);
}

// ---------------- zero output rows of empty segments ----------------
__global__ void fix_empty(const int* __restrict__ rs, float* __restrict__ out) {
    int g = blockIdx.x * blockDim.x + threadIdx.x;
    if (g >= GRIDN || (rs[g + 1] - rs[g]) != 0) return;
    float* row = out + (size_t)g * HID;
    for (int c = 0; c < HID; c++) row[c] = 0.f;
}

// ---------------- fallback: 384-wide seg machinery (proven) ----------------
__global__ void seg_partial(const int* __restrict__ edges, int e0, int e1,
                            const __hip_bfloat16* __restrict__ m3c, float* __restrict__ out) {
    int g = blockIdx.x;
    int l = e0, r = e1;
    while (l < r) { int mid = (l + r) >> 1; if (edges[2 * mid] < g) l = mid + 1; else r = mid; }
    int lo = l;
    r = e1;
    while (l < r) { int mid = (l + r) >> 1; if (edges[2 * mid] <= g) l = mid + 1; else r = mid; }
    int hi = l;
    if (lo >= hi) return;
    int c = threadIdx.x;
    float s0 = 0.f, s1 = 0.f, s2 = 0.f;
    for (int e = lo; e < hi; e++) {
        const __hip_bfloat16* rp = m3c + (size_t)(e - e0) * HID;
        s0 += __bfloat162float(rp[c]);
        s1 += __bfloat162float(rp[c + 128]);
        s2 += __bfloat162float(rp[c + 256]);
    }
    float* orow = out + (size_t)g * HID;
    orow[c] += s0;
    orow[c + 128] += s1;
    orow[c + 256] += s2;
}

__global__ void seg_div(const int* __restrict__ edges, float* __restrict__ out) {
    int g = blockIdx.x;
    int l = 0, r = NEDGE;
    while (l < r) { int mid = (l + r) >> 1; if (edges[2 * mid] < g) l = mid + 1; else r = mid; }
    int lo = l;
    r = NEDGE;
    while (l < r) { int mid = (l + r) >> 1; if (edges[2 * mid] <= g) l = mid + 1; else r = mid; }
    int cnt = l - lo;
    float inv = 1.0f / (float)max(cnt, 1);
    int c = threadIdx.x;
    float* orow = out + (size_t)g * HID;
    orow[c] *= inv;
    orow[c + 128] *= inv;
    orow[c + 256] *= inv;
}

extern "C" void kernel_launch(void* const* d_in, const int* in_sizes, int n_in,
                              void* d_out, int out_size, void* d_ws, size_t ws_size,
                              hipStream_t stream) {
    const float* x        = (const float*)d_in[0];
    const float* mesh_pos = (const float*)d_in[1];
    const float* grid_pos = (const float*)d_in[2];
    const int*   edges    = (const int*)d_in[3];
    const float* w1  = (const float*)d_in[4];
    const float* b1  = (const float*)d_in[5];
    const float* w2  = (const float*)d_in[6];
    const float* b2  = (const float*)d_in[7];
    const float* w3  = (const float*)d_in[8];
    const float* b3  = (const float*)d_in[9];
    const float* wm1 = (const float*)d_in[10];
    const float* bm1 = (const float*)d_in[11];
    const float* wm2 = (const float*)d_in[12];
    const float* bm2 = (const float*)d_in[13];
    const float* wm3 = (const float*)d_in[14];
    const float* bm3 = (const float*)d_in[15];
    float* out = (float*)d_out;

    auto rnd = [](size_t b) { return (b + 255) & ~(size_t)255; };
    const size_t wbytes = rnd((size_t)384 * 384 * 2) + rnd((size_t)768 * 576 * 2) +
                          rnd((size_t)768 * 192 * 2) + rnd((size_t)768 * 768 * 2) +
                          rnd((size_t)384 * 768 * 2) + rnd(768 * 4) * 2 +
                          rnd((size_t)(GRIDN + 1) * 4);
    const size_t szU    = rnd((size_t)NMESH * 768 * 2);     // 76.8 MB
    const size_t szV    = rnd((size_t)GRIDN * 768 * 2);     // 50.33 MB
    const size_t szMesh = rnd((size_t)NMESH * 576 * 2);     // 57.6 MB
    const size_t szS2   = rnd((size_t)GRIDN * 384 * 4);     // 50.33 MB (half-sums)
    const size_t szM1   = rnd((size_t)32768 * 768 * 2);     // 50.33 MB

    // fold path: weights + U + V + S2 + m1c = ~231.2 MB (engaged in r18)
    const size_t NEED_FOLD = wbytes + szU + szV + szS2 + szM1;

    char* p = (char*)d_ws;
    auto alloc = [&](size_t b) { char* r = p; p += (b + 255) & ~(size_t)255; return r; };

    // common prep allocations
    __hip_bfloat16* wt2   = (__hip_bfloat16*)alloc((size_t)384 * 384 * 2);
    __hip_bfloat16* wtm1f = (__hip_bfloat16*)alloc((size_t)768 * 576 * 2);
    __hip_bfloat16* wtm1v = (__hip_bfloat16*)alloc((size_t)768 * 192 * 2);
    __hip_bfloat16* wtm2  = (__hip_bfloat16*)alloc((size_t)768 * 768 * 2);
    __hip_bfloat16* wtm3  = (__hip_bfloat16*)alloc((size_t)384 * 768 * 2);
    float* zeros          = (float*)alloc(768 * 4);
    float* bf             = (float*)alloc(768 * 4);
    int* rs               = (int*)alloc((size_t)(GRIDN + 1) * 4);
    char* Ur              = alloc(szU);
    char* Vr              = alloc(szV);

    __hip_bfloat16* U  = (__hip_bfloat16*)Ur;
    __hip_bfloat16* V  = (__hip_bfloat16*)Vr;
    __hip_bfloat16* h1 = (__hip_bfloat16*)Ur;                 // dead before U

    hipMemsetAsync(zeros, 0, 768 * 4, stream);

    transpose_to_bf16<<<(384 * 384 + 255) / 256, 256, 0, stream>>>(w2, wt2, 384, 384, 0);
    transpose_to_bf16<<<(768 * 192 + 255) / 256, 256, 0, stream>>>(wm1, wtm1v, 192, 768, 576);
    transpose_to_bf16<<<(768 * 768 + 255) / 256, 256, 0, stream>>>(wm2, wtm2, 768, 768, 0);
    transpose_to_bf16<<<(768 * 384 + 255) / 256, 256, 0, stream>>>(wm3, wtm3, 768, 384, 0);
    fold_w3_wm1<<<(576 * 768 + 255) / 256, 256, 0, stream>>>(w3, wm1, wtm1f);
    fold_bias<<<3, 256, 0, stream>>>(b3, wm1, bm1, bf);
    calc_rowstart<<<(GRIDN + 1 + 255) / 256, 256, 0, stream>>>(edges, rs);

    if (ws_size >= NEED_FOLD) {
        // ========== FOLD PATH (231 MB): 256^2-tile GEMMs for U, V, m2+split-atomic-seg ==========
        const int CH = 32768;
        const int NCH = NEDGE / CH;
        char* S2r = alloc(szS2);                  // half-sums, cols [384,768)
        char* CA  = alloc(szM1);                  // m1c

        float* S2             = (float*)S2r;
        __hip_bfloat16* meshf2 = (__hip_bfloat16*)S2r;            // [h2|pe], spans S2+CA pre-loop
        __hip_bfloat16* gridf  = (__hip_bfloat16*)(S2r + szMesh);
        __hip_bfloat16* m1c    = (__hip_bfloat16*)CA;
        __hip_bfloat16* meanM2 = (__hip_bfloat16*)CA;             // reuse after loop

        embed_kernel<<<(NMESH * 96 + 255) / 256, 256, 0, stream>>>(mesh_pos, meshf2, NMESH, 576, 384);
        embed_kernel<<<(GRIDN * 96 + 255) / 256, 256, 0, stream>>>(grid_pos, gridf, GRIDN, 192, 0);

        lin1_kernel<<<(NMESH * HID + 255) / 256, 256, 0, stream>>>(x, w1, b1, h1);

        // meshf2[:, :384] = h2 = gelu(h1 @ w2 + b2)   (ldc=576, 128^2 kernel)
        mfma_gemm<true, false, false><<<dim3(3, 391), 256, 0, stream>>>(
            h1, wt2, b2, meshf2, nullptr, NMESH, 384, 384, 576, nullptr, 0);
        // U = meshf2 @ Wfold + bf   (256^2 kernel)
        mfma_gemm256<false, false><<<dim3(3, 196), 512, 0, stream>>>(
            meshf2, wtm1f, bf, U, nullptr, NMESH, 768, 576, 768, nullptr, 0);
        // V = gridf @ wm1[576:]     (256^2 kernel)
        mfma_gemm256<false, false><<<dim3(3, 128), 512, 0, stream>>>(
            gridf, wtm1v, zeros, V, nullptr, GRIDN, 768, 192, 768, nullptr, 0);

        // embeds now dead: zero the split accumulator (d_out cols 0-383, S2 cols 384-767)
        hipMemsetAsync(out, 0, (size_t)GRIDN * 384 * 4, stream);
        hipMemsetAsync(S2, 0, (size_t)GRIDN * 384 * 4, stream);

        for (int c = 0; c < NCH; c++) {
            int e0 = c * CH;
            fuse_m1<<<(CH * 96 + 255) / 256, 256, 0, stream>>>(U, V, edges, e0, CH, m1c);
            // split_sums[grid[e]] += gelu(m1c @ wm2 + bm2)   (256^2 kernel, atomic-seg)
            mfma_gemm256<true, true><<<dim3(3, CH / 256), 512, 0, stream>>>(
                m1c, wtm2, bm2, out, S2, CH, 768, 768, 768, edges, e0);
        }

        mean_bf16<<<(GRIDN * 768 / 4 + 255) / 256, 256, 0, stream>>>(out, S2, rs, meanM2);
        // out = meanM2 @ wm3 + bm3   (f32, 128^2 kernel)
        mfma_gemm<false, true, false><<<dim3(3, 256), 256, 0, stream>>>(
            meanM2, wtm3, bm3, out, nullptr, GRIDN, 384, 768, 384, nullptr, 0);
        fix_empty<<<(GRIDN + 255) / 256, 256, 0, stream>>>(rs, out);
    } else {
        // ========== FALLBACK: r17's proven 128^2 path (separate m2 + m3 + 384-wide seg) ==========
        const int CH = 32768;
        const int NCH = NEDGE / CH;
        char* CA = alloc(2 * rnd((size_t)CH * 768 * 2));

        __hip_bfloat16* meshf2 = (__hip_bfloat16*)CA;
        __hip_bfloat16* gridf  = (__hip_bfloat16*)(CA + szMesh);
        __hip_bfloat16* m1c    = (__hip_bfloat16*)CA;
        __hip_bfloat16* m2c    = (__hip_bfloat16*)(CA + rnd((size_t)CH * 768 * 2));
        __hip_bfloat16* m3c    = m1c;

        hipMemsetAsync(out, 0, (size_t)GRIDN * HID * 4, stream);

        embed_kernel<<<(NMESH * 96 + 255) / 256, 256, 0, stream>>>(mesh_pos, meshf2, NMESH, 576, 384);
        embed_kernel<<<(GRIDN * 96 + 255) / 256, 256, 0, stream>>>(grid_pos, gridf, GRIDN, 192, 0);

        lin1_kernel<<<(NMESH * HID + 255) / 256, 256, 0, stream>>>(x, w1, b1, h1);

        mfma_gemm<true, false, false><<<dim3(3, 391), 256, 0, stream>>>(
            h1, wt2, b2, meshf2, nullptr, NMESH, 384, 384, 576, nullptr, 0);
        mfma_gemm<false, false, false><<<dim3(6, 391), 256, 0, stream>>>(
            meshf2, wtm1f, bf, U, nullptr, NMESH, 768, 576, 768, nullptr, 0);
        mfma_gemm<false, false, false><<<dim3(6, 256), 256, 0, stream>>>(
            gridf, wtm1v, zeros, V, nullptr, GRIDN, 768, 192, 768, nullptr, 0);

        for (int c = 0; c < NCH; c++) {
            int e0 = c * CH;
            fuse_m1<<<(CH * 96 + 255) / 256, 256, 0, stream>>>(U, V, edges, e0, CH, m1c);
            mfma_gemm<true, false, false><<<dim3(6, CH / 128), 256, 0, stream>>>(
                m1c, wtm2, bm2, m2c, nullptr, CH, 768, 768, 768, nullptr, 0);
            mfma_gemm<false, false, false><<<dim3(3, CH / 128), 256, 0, stream>>>(
                m2c, wtm3, bm3, m3c, nullptr, CH, 384, 768, 384, nullptr, 0);
            seg_partial<<<GRIDN, 128, 0, stream>>>(edges, e0, e0 + CH, m3c, out);
        }

        seg_div<<<GRIDN, 128, 0, stream>>>(edges, out);
    }
}

// Round 20
// 1078.083 us; speedup vs baseline: 1.1031x; 1.1031x over previous
//
#include <hip/hip_runtime.h>
#include <hip/hip_bf16.h>

#define NMESH 50000
#define GRIDN 32768
#define NEDGE 131072
#define HID 384

using f32x4 = __attribute__((ext_vector_type(4))) float;
using bfrag = __attribute__((ext_vector_type(8))) short;
using i32x4 = __attribute__((ext_vector_type(4))) int;

__device__ __forceinline__ float gelu_f(float v) {
    return 0.5f * v * (1.0f + erff(v * 0.70710678118654752f));
}

__device__ __forceinline__ void load_lds16(const void* g, void* l) {
    __builtin_amdgcn_global_load_lds(
        (const __attribute__((address_space(1))) void*)g,
        (__attribute__((address_space(3))) void*)l,
        16, 0, 0);
}

// bijective XCD-chunking swizzle (m204)
__device__ __forceinline__ void xcd_swizzle(int& bx, int& by) {
    int gx = gridDim.x;
    int nwg = gx * gridDim.y;
    int l = blockIdx.y * gx + blockIdx.x;
    int q = nwg >> 3, r = nwg & 7;
    int xcd = l & 7, pos = l >> 3;
    int nl = (xcd < r ? xcd * (q + 1) : r * (q + 1) + (xcd - r) * q) + pos;
    by = nl / gx;
    bx = nl - by * gx;
}

// unpack 8+8 bf16, add f32, gelu, repack
__device__ __forceinline__ bfrag fuse8(i32x4 u, i32x4 v) {
    bfrag ub = *reinterpret_cast<bfrag*>(&u);
    bfrag vb = *reinterpret_cast<bfrag*>(&v);
    bfrag o;
    #pragma unroll
    for (int i = 0; i < 8; i++) {
        unsigned short us = (unsigned short)ub[i], vs = (unsigned short)vb[i];
        float a = __bfloat162float(*(__hip_bfloat16*)&us) + __bfloat162float(*(__hip_bfloat16*)&vs);
        a = gelu_f(a);
        __hip_bfloat16 hb = __float2bfloat16(a);
        o[i] = *(short*)&hb;
    }
    return o;
}

// ---------------- weight transpose + bf16 cast: wt[n*K+k] = w[(k0+k)*N+n] ----------------
__global__ void transpose_to_bf16(const float* __restrict__ w, __hip_bfloat16* __restrict__ wt,
                                  int K, int N, int k0) {
    int idx = blockIdx.x * blockDim.x + threadIdx.x;
    if (idx >= K * N) return;
    int n = idx / K;
    int k = idx - n * K;
    wt[idx] = __float2bfloat16(w[(size_t)(k0 + k) * N + n]);
}

// ---------------- fold w3 into wm1 ----------------
__global__ void fold_w3_wm1(const float* __restrict__ w3, const float* __restrict__ wm1,
                            __hip_bfloat16* __restrict__ wtf) {
    int idx = blockIdx.x * blockDim.x + threadIdx.x;
    if (idx >= 576 * 768) return;
    int k = idx / 768;
    int n = idx - k * 768;
    float acc;
    if (k < 384) {
        acc = 0.f;
        #pragma unroll 4
        for (int j = 0; j < 384; j++)
            acc = fmaf(w3[k * 384 + j], wm1[j * 768 + n], acc);
    } else {
        acc = wm1[(size_t)k * 768 + n];
    }
    wtf[(size_t)n * 576 + k] = __float2bfloat16(acc);
}

// ---------------- folded bias ----------------
__global__ void fold_bias(const float* __restrict__ b3, const float* __restrict__ wm1,
                          const float* __restrict__ bm1, float* __restrict__ bf) {
    int n = blockIdx.x * blockDim.x + threadIdx.x;
    if (n >= 768) return;
    float acc = bm1[n];
    #pragma unroll 4
    for (int k = 0; k < 384; k++) acc = fmaf(b3[k], wm1[(size_t)k * 768 + n], acc);
    bf[n] = acc;
}

// ---------------- rowstart[g] = lower_bound(edges[:,0], g) ----------------
__global__ void calc_rowstart(const int* __restrict__ edges, int* __restrict__ rs) {
    int g = blockIdx.x * blockDim.x + threadIdx.x;
    if (g > GRIDN) return;
    int l = 0, r = NEDGE;
    while (l < r) { int m = (l + r) >> 1; if (edges[2 * m] < g) l = m + 1; else r = m; }
    rs[g] = l;
}

// ---------------- sincos positional embedding ----------------
__global__ void embed_kernel(const float* __restrict__ pos, __hip_bfloat16* __restrict__ outp,
                             int n, int stride, int coloff) {
    int idx = blockIdx.x * blockDim.x + threadIdx.x;
    if (idx >= n * 96) return;
    int nn = idx / 96;
    int rr = idx - nn * 96;
    int d = rr >> 5;
    int k = rr & 31;
    float v = pos[nn * 3 + d];
    float omega = expf(-0.28782313662425575f * (float)k);  // ln(10000)/32
    float a = v * omega;
    __hip_bfloat16* o = outp + (size_t)nn * stride + coloff + d * 64 + k;
    o[0]  = __float2bfloat16(sinf(a));
    o[32] = __float2bfloat16(cosf(a));
}

// ---------------- layer 1 ----------------
__global__ void lin1_kernel(const float* __restrict__ x, const float* __restrict__ w,
                            const float* __restrict__ b, __hip_bfloat16* __restrict__ h1) {
    int idx = blockIdx.x * blockDim.x + threadIdx.x;
    if (idx >= NMESH * HID) return;
    int m = idx / HID;
    int n = idx - m * HID;
    float acc = b[n];
    const float* xr = x + m * 16;
    #pragma unroll
    for (int k = 0; k < 16; k++) acc = fmaf(xr[k], w[k * HID + n], acc);
    h1[idx] = __float2bfloat16(gelu_f(acc));
}

// ======================================================================
// 128x128-tile bf16 MFMA GEMM (proven body; 3-buffer counted-vmcnt,
// pre-swizzled global_load_lds, 0 conflicts/no spill measured).
// Epilogues: bf16 / f32 / split-SEGA atomics (r18-proven).
// ======================================================================
template<bool GELU, bool F32OUT, bool SEGA>
__launch_bounds__(256, 3)
__global__ void mfma_gemm(const __hip_bfloat16* __restrict__ A,
                          const __hip_bfloat16* __restrict__ Wt,
                          const float* __restrict__ bias,
                          void* __restrict__ Cv, void* __restrict__ Cv2,
                          int M, int N, int K, int ldc,
                          const int* __restrict__ seg_edges, int seg_e0) {
    __shared__ __align__(16) __hip_bfloat16 As[3][4096];
    __shared__ __align__(16) __hip_bfloat16 Bs[3][4096];

    const int t = threadIdx.x;
    const int lane = t & 63;
    const int wave = t >> 6;
    const int wm0 = (wave >> 1) * 64;
    const int wn0 = (wave & 1) * 64;

    int bx, by;
    xcd_swizzle(bx, by);
    const int row0 = by * 128;
    const int col0 = bx * 128;

    const int rS0 = t >> 2;
    const int rS1 = rS0 + 64;
    const int kcS = (t & 3) ^ ((t >> 3) & 3);

    const __hip_bfloat16* aP0 = A + (size_t)min(row0 + rS0, M - 1) * K;
    const __hip_bfloat16* aP1 = A + (size_t)min(row0 + rS1, M - 1) * K;
    const __hip_bfloat16* bP0 = Wt + (size_t)(col0 + rS0) * K;
    const __hip_bfloat16* bP1 = Wt + (size_t)(col0 + rS1) * K;

    const int off0 = (wave * 64) * 16;
    const int off1 = (256 + wave * 64) * 16;

    f32x4 acc[4][4] = {};

    const int kq = lane >> 4;
    const int lr = lane & 15;
    const int kqx = kq ^ ((lr >> 1) & 3);
    const int rdA = (wm0 + lr) * 32 + kqx * 8;
    const int rdB = (wn0 + lr) * 32 + kqx * 8;

    const int nsteps = K >> 5;

    auto stage = [&](int ks, int buf) {
        int k = ks * 32 + kcS * 8;
        load_lds16(aP0 + k, (char*)As[buf] + off0);
        load_lds16(aP1 + k, (char*)As[buf] + off1);
        load_lds16(bP0 + k, (char*)Bs[buf] + off0);
        load_lds16(bP1 + k, (char*)Bs[buf] + off1);
    };

    stage(0, 0);
    stage(1, 1);

    int cur = 0;
    int stg = 2;
    for (int ks = 0; ks < nsteps; ks++) {
        if (ks + 1 < nsteps) {
            asm volatile("s_waitcnt vmcnt(4)" ::: "memory");
        } else {
            asm volatile("s_waitcnt vmcnt(0)" ::: "memory");
        }
        __builtin_amdgcn_s_barrier();
        if (ks + 2 < nsteps) stage(ks + 2, stg);

        bfrag aF[4], bF[4];
        #pragma unroll
        for (int i = 0; i < 4; i++) {
            aF[i] = *reinterpret_cast<const bfrag*>(&As[cur][rdA + i * 512]);
            bF[i] = *reinterpret_cast<const bfrag*>(&Bs[cur][rdB + i * 512]);
        }
        asm volatile("s_waitcnt lgkmcnt(0)" ::: "memory");
        __builtin_amdgcn_sched_barrier(0);
        __builtin_amdgcn_s_setprio(1);
        #pragma unroll
        for (int i = 0; i < 4; i++) {
            #pragma unroll
            for (int j = 0; j < 4; j++) {
                acc[i][j] = __builtin_amdgcn_mfma_f32_16x16x32_bf16(aF[i], bF[j], acc[i][j], 0, 0, 0);
            }
        }
        __builtin_amdgcn_s_setprio(0);

        cur = (cur == 2) ? 0 : cur + 1;
        stg = (stg == 2) ? 0 : stg + 1;
    }

    if constexpr (SEGA) {
        float* o0 = (float*)Cv;
        float* o1 = (float*)Cv2;
        #pragma unroll
        for (int i = 0; i < 4; i++) {
            int rbase = seg_e0 + row0 + wm0 + i * 16 + kq * 4;
            int g0 = seg_edges[2 * (rbase + 0)];
            int g1 = seg_edges[2 * (rbase + 1)];
            int g2 = seg_edges[2 * (rbase + 2)];
            int g3 = seg_edges[2 * (rbase + 3)];
            bool same = (g0 == g1) & (g1 == g2) & (g2 == g3);
            #pragma unroll
            for (int j = 0; j < 4; j++) {
                int col = col0 + wn0 + j * 16 + lr;
                float* base = (col < 384) ? (o0 + col) : (o1 + (col - 384));
                float v0 = gelu_f(acc[i][j][0] + bias[col]);
                float v1 = gelu_f(acc[i][j][1] + bias[col]);
                float v2 = gelu_f(acc[i][j][2] + bias[col]);
                float v3 = gelu_f(acc[i][j][3] + bias[col]);
                if (same) {
                    unsafeAtomicAdd(base + (size_t)g0 * 384, v0 + v1 + v2 + v3);
                } else {
                    unsafeAtomicAdd(base + (size_t)g0 * 384, v0);
                    unsafeAtomicAdd(base + (size_t)g1 * 384, v1);
                    unsafeAtomicAdd(base + (size_t)g2 * 384, v2);
                    unsafeAtomicAdd(base + (size_t)g3 * 384, v3);
                }
            }
        }
    } else {
        #pragma unroll
        for (int i = 0; i < 4; i++) {
            #pragma unroll
            for (int j = 0; j < 4; j++) {
                #pragma unroll
                for (int r = 0; r < 4; r++) {
                    int row = row0 + wm0 + i * 16 + kq * 4 + r;
                    int col = col0 + wn0 + j * 16 + lr;
                    if (row < M) {
                        float v = acc[i][j][r] + bias[col];
                        if constexpr (GELU) v = gelu_f(v);
                        if constexpr (F32OUT)
                            ((float*)Cv)[(size_t)row * ldc + col] = v;
                        else
                            ((__hip_bfloat16*)Cv)[(size_t)row * ldc + col] = __float2bfloat16(v);
                    }
                }
            }
        }
    }
}

// ======================================================================
// FUSED m2 GEMM + split-SEGA: sums[grid[e]] += gelu(gelu(U[mi]+V[gi]) @ wm2 + bm2).
// A-side: reg-staged gather + fuse8 + ds_write with sigma=2kc slot swizzle
//   (write groups hit {0,2,4,6,1,3,5,7} mod 8 -- the r5-measured-zero pattern).
// B-side: pre-swizzled global_load_lds (r6-proven pair, 0 conflicts).
// 2-phase dbuf (32KB LDS -> 3 blocks/CU); syncthreads drains both paths.
// Deletes fuse_m1 launches AND the m1c HBM round-trip entirely.
// ======================================================================
__launch_bounds__(256, 3)
__global__ void mfma_gemm_m2s(const __hip_bfloat16* __restrict__ U,
                              const __hip_bfloat16* __restrict__ V,
                              const int* __restrict__ edges, int e0,
                              const __hip_bfloat16* __restrict__ Wt,
                              const float* __restrict__ bias,
                              float* __restrict__ o0, float* __restrict__ o1) {
    const int K = 768;
    __shared__ __align__(16) __hip_bfloat16 As[2][4096];
    __shared__ __align__(16) __hip_bfloat16 Bs[2][4096];

    const int t = threadIdx.x;
    const int lane = t & 63;
    const int wave = t >> 6;
    const int wm0 = (wave >> 1) * 64;
    const int wn0 = (wave & 1) * 64;

    int bx, by;
    xcd_swizzle(bx, by);
    const int row0 = by * 128;
    const int col0 = bx * 128;

    // A staging (registers): rows rS0, rS0+64; k-chunk kcA
    const int kcA = t & 3;
    const int rS0 = t >> 2;
    const int rS1 = rS0 + 64;
    const int er0 = e0 + row0 + rS0;
    const int er1 = e0 + row0 + rS1;
    const __hip_bfloat16* uP0 = U + (size_t)edges[2 * er0 + 1] * 768;
    const __hip_bfloat16* vP0 = V + (size_t)edges[2 * er0 + 0] * 768;
    const __hip_bfloat16* uP1 = U + (size_t)edges[2 * er1 + 1] * 768;
    const __hip_bfloat16* vP1 = V + (size_t)edges[2 * er1 + 0] * 768;
    // LDS dest (elem offsets), slot(kc,row) = kc*128 + (row^(2kc))
    const int dA0 = kcA * 1024 + ((rS0 ^ (kcA << 1)) << 3);
    const int dA1 = kcA * 1024 + ((rS1 ^ (kcA << 1)) << 3);

    // B staging (global_load_lds, pre-swizzled source)
    const int kcB = (t & 3) ^ ((t >> 3) & 3);
    const __hip_bfloat16* bP0 = Wt + (size_t)(col0 + rS0) * K;
    const __hip_bfloat16* bP1 = Wt + (size_t)(col0 + rS1) * K;
    const int offB0 = (wave * 64) * 16;
    const int offB1 = (256 + wave * 64) * 16;

    f32x4 acc[4][4] = {};

    const int kq = lane >> 4;
    const int lr = lane & 15;
    // A fragment read (kc-major): kq*1024 + wm0*8 + (lr^2kq)*8, frag i at +i*128
    const int rdA = kq * 1024 + ((lr ^ (kq << 1)) << 3) + wm0 * 8;
    // B fragment read (row-major, kc permuted): (wn0+lr)*32 + kqx*8, frag j at +j*512
    const int kqx = kq ^ ((lr >> 1) & 3);
    const int rdB = (wn0 + lr) * 32 + kqx * 8;

    const int nsteps = K >> 5;   // 24

    // prologue: fill buffer 0
    {
        int k = kcA * 8;
        i32x4 u0 = *reinterpret_cast<const i32x4*>(uP0 + k);
        i32x4 v0 = *reinterpret_cast<const i32x4*>(vP0 + k);
        i32x4 u1 = *reinterpret_cast<const i32x4*>(uP1 + k);
        i32x4 v1 = *reinterpret_cast<const i32x4*>(vP1 + k);
        *reinterpret_cast<bfrag*>(&As[0][dA0]) = fuse8(u0, v0);
        *reinterpret_cast<bfrag*>(&As[0][dA1]) = fuse8(u1, v1);
        int kb = kcB * 8;
        load_lds16(bP0 + kb, (char*)Bs[0] + offB0);
        load_lds16(bP1 + kb, (char*)Bs[0] + offB1);
    }
    __syncthreads();

    int cur = 0;
    for (int ks = 0; ks < nsteps; ks++) {
        const bool more = (ks + 1 < nsteps);
        i32x4 u0, v0, u1, v1;
        if (more) {
            int k = (ks + 1) * 32 + kcA * 8;
            u0 = *reinterpret_cast<const i32x4*>(uP0 + k);
            v0 = *reinterpret_cast<const i32x4*>(vP0 + k);
            u1 = *reinterpret_cast<const i32x4*>(uP1 + k);
            v1 = *reinterpret_cast<const i32x4*>(vP1 + k);
            int kb = (ks + 1) * 32 + kcB * 8;
            load_lds16(bP0 + kb, (char*)Bs[cur ^ 1] + offB0);
            load_lds16(bP1 + kb, (char*)Bs[cur ^ 1] + offB1);
        }

        bfrag aF[4], bF[4];
        #pragma unroll
        for (int i = 0; i < 4; i++) {
            aF[i] = *reinterpret_cast<const bfrag*>(&As[cur][rdA + i * 128]);
            bF[i] = *reinterpret_cast<const bfrag*>(&Bs[cur][rdB + i * 512]);
        }
        #pragma unroll
        for (int i = 0; i < 4; i++) {
            #pragma unroll
            for (int j = 0; j < 4; j++) {
                acc[i][j] = __builtin_amdgcn_mfma_f32_16x16x32_bf16(aF[i], bF[j], acc[i][j], 0, 0, 0);
            }
        }
        if (more) {
            *reinterpret_cast<bfrag*>(&As[cur ^ 1][dA0]) = fuse8(u0, v0);
            *reinterpret_cast<bfrag*>(&As[cur ^ 1][dA1]) = fuse8(u1, v1);
        }
        __syncthreads();
        cur ^= 1;
    }

    // split-SEGA epilogue (r18-proven): sums[grid[e]][col] += gelu(acc + bias)
    #pragma unroll
    for (int i = 0; i < 4; i++) {
        int rbase = e0 + row0 + wm0 + i * 16 + kq * 4;
        int g0 = edges[2 * (rbase + 0)];
        int g1 = edges[2 * (rbase + 1)];
        int g2 = edges[2 * (rbase + 2)];
        int g3 = edges[2 * (rbase + 3)];
        bool same = (g0 == g1) & (g1 == g2) & (g2 == g3);
        #pragma unroll
        for (int j = 0; j < 4; j++) {
            int col = col0 + wn0 + j * 16 + lr;
            float* base = (col < 384) ? (o0 + col) : (o1 + (col - 384));
            float v0 = gelu_f(acc[i][j][0] + bias[col]);
            float v1 = gelu_f(acc[i][j][1] + bias[col]);
            float v2 = gelu_f(acc[i][j][2] + bias[col]);
            float v3 = gelu_f(acc[i][j][3] + bias[col]);
            if (same) {
                unsafeAtomicAdd(base + (size_t)g0 * 384, v0 + v1 + v2 + v3);
            } else {
                unsafeAtomicAdd(base + (size_t)g0 * 384, v0);
                unsafeAtomicAdd(base + (size_t)g1 * 384, v1);
                unsafeAtomicAdd(base + (size_t)g2 * 384, v2);
                unsafeAtomicAdd(base + (size_t)g3 * 384, v3);
            }
        }
    }
}

// ---------------- m1 fuse (fallback only) ----------------
__global__ void fuse_m1(const __hip_bfloat16* __restrict__ U, const __hip_bfloat16* __restrict__ V,
                        const int* __restrict__ edges, int e0, int ne,
                        __hip_bfloat16* __restrict__ m1c) {
    int idx = blockIdx.x * blockDim.x + threadIdx.x;
    if (idx >= ne * 96) return;
    int e = idx / 96;
    int c8 = (idx - e * 96) * 8;
    int ge = e0 + e;
    int mi = edges[2 * ge + 1];
    int gi = edges[2 * ge + 0];
    i32x4 u = *reinterpret_cast<const i32x4*>(U + (size_t)mi * 768 + c8);
    i32x4 v = *reinterpret_cast<const i32x4*>(V + (size_t)gi * 768 + c8);
    *reinterpret_cast<bfrag*>(m1c + (size_t)e * 768 + c8) = fuse8(u, v);
}

// ---------------- meanM2 = bf16(split_sums / max(cnt,1)) ----------------
__global__ void mean_bf16(const float* __restrict__ s0, const float* __restrict__ s1,
                          const int* __restrict__ rs, __hip_bfloat16* __restrict__ mm) {
    int idx = blockIdx.x * blockDim.x + threadIdx.x;
    int base = idx * 4;
    if (base >= GRIDN * 768) return;
    int g = base / 768;
    int c = base - g * 768;
    int cnt = rs[g + 1] - rs[g];
    float inv = 1.0f / (float)max(cnt, 1);
    float4 v = (c < 384) ? *reinterpret_cast<const float4*>(s0 + (size_t)g * 384 + c)
                         : *reinterpret_cast<const float4*>(s1 + (size_t)g * 384 + (c - 384));
    __hip_bfloat16 o[4] = {__float2bfloat16(v.x * inv), __float2bfloat16(v.y * inv),
                           __float2bfloat16(v.z * inv), __float2bfloat16(v.w * inv)};
    *reinterpret_cast<uint2*>(mm + base) = *reinterpret_cast<const uint2*>(o);
}

// ---------------- zero output rows of empty segments ----------------
__global__ void fix_empty(const int* __restrict__ rs, float* __restrict__ out) {
    int g = blockIdx.x * blockDim.x + threadIdx.x;
    if (g >= GRIDN || (rs[g + 1] - rs[g]) != 0) return;
    float* row = out + (size_t)g * HID;
    for (int c = 0; c < HID; c++) row[c] = 0.f;
}

// ---------------- fallback: 384-wide seg machinery (proven) ----------------
__global__ void seg_partial(const int* __restrict__ edges, int e0, int e1,
                            const __hip_bfloat16* __restrict__ m3c, float* __restrict__ out) {
    int g = blockIdx.x;
    int l = e0, r = e1;
    while (l < r) { int mid = (l + r) >> 1; if (edges[2 * mid] < g) l = mid + 1; else r = mid; }
    int lo = l;
    r = e1;
    while (l < r) { int mid = (l + r) >> 1; if (edges[2 * mid] <= g) l = mid + 1; else r = mid; }
    int hi = l;
    if (lo >= hi) return;
    int c = threadIdx.x;
    float s0 = 0.f, s1 = 0.f, s2 = 0.f;
    for (int e = lo; e < hi; e++) {
        const __hip_bfloat16* rp = m3c + (size_t)(e - e0) * HID;
        s0 += __bfloat162float(rp[c]);
        s1 += __bfloat162float(rp[c + 128]);
        s2 += __bfloat162float(rp[c + 256]);
    }
    float* orow = out + (size_t)g * HID;
    orow[c] += s0;
    orow[c + 128] += s1;
    orow[c + 256] += s2;
}

__global__ void seg_div(const int* __restrict__ edges, float* __restrict__ out) {
    int g = blockIdx.x;
    int l = 0, r = NEDGE;
    while (l < r) { int mid = (l + r) >> 1; if (edges[2 * mid] < g) l = mid + 1; else r = mid; }
    int lo = l;
    r = NEDGE;
    while (l < r) { int mid = (l + r) >> 1; if (edges[2 * mid] <= g) l = mid + 1; else r = mid; }
    int cnt = l - lo;
    float inv = 1.0f / (float)max(cnt, 1);
    int c = threadIdx.x;
    float* orow = out + (size_t)g * HID;
    orow[c] *= inv;
    orow[c + 128] *= inv;
    orow[c + 256] *= inv;
}

extern "C" void kernel_launch(void* const* d_in, const int* in_sizes, int n_in,
                              void* d_out, int out_size, void* d_ws, size_t ws_size,
                              hipStream_t stream) {
    const float* x        = (const float*)d_in[0];
    const float* mesh_pos = (const float*)d_in[1];
    const float* grid_pos = (const float*)d_in[2];
    const int*   edges    = (const int*)d_in[3];
    const float* w1  = (const float*)d_in[4];
    const float* b1  = (const float*)d_in[5];
    const float* w2  = (const float*)d_in[6];
    const float* b2  = (const float*)d_in[7];
    const float* w3  = (const float*)d_in[8];
    const float* b3  = (const float*)d_in[9];
    const float* wm1 = (const float*)d_in[10];
    const float* bm1 = (const float*)d_in[11];
    const float* wm2 = (const float*)d_in[12];
    const float* bm2 = (const float*)d_in[13];
    const float* wm3 = (const float*)d_in[14];
    const float* bm3 = (const float*)d_in[15];
    float* out = (float*)d_out;

    auto rnd = [](size_t b) { return (b + 255) & ~(size_t)255; };
    const size_t wbytes = rnd((size_t)384 * 384 * 2) + rnd((size_t)768 * 576 * 2) +
                          rnd((size_t)768 * 192 * 2) + rnd((size_t)768 * 768 * 2) +
                          rnd((size_t)384 * 768 * 2) + rnd(768 * 4) * 2 +
                          rnd((size_t)(GRIDN + 1) * 4);
    const size_t szU    = rnd((size_t)NMESH * 768 * 2);     // 76.8 MB
    const size_t szV    = rnd((size_t)GRIDN * 768 * 2);     // 50.33 MB
    const size_t szMesh = rnd((size_t)NMESH * 576 * 2);     // 57.6 MB
    const size_t szS2   = rnd((size_t)GRIDN * 384 * 4);     // 50.33 MB (half-sums)
    const size_t szM1   = rnd((size_t)32768 * 768 * 2);     // 50.33 MB

    // fold path: same footprint as r18 (engaged) -- m1c region now hosts meanM2 only
    const size_t NEED_FOLD = wbytes + szU + szV + szS2 + szM1;

    char* p = (char*)d_ws;
    auto alloc = [&](size_t b) { char* r = p; p += (b + 255) & ~(size_t)255; return r; };

    // common prep allocations
    __hip_bfloat16* wt2   = (__hip_bfloat16*)alloc((size_t)384 * 384 * 2);
    __hip_bfloat16* wtm1f = (__hip_bfloat16*)alloc((size_t)768 * 576 * 2);
    __hip_bfloat16* wtm1v = (__hip_bfloat16*)alloc((size_t)768 * 192 * 2);
    __hip_bfloat16* wtm2  = (__hip_bfloat16*)alloc((size_t)768 * 768 * 2);
    __hip_bfloat16* wtm3  = (__hip_bfloat16*)alloc((size_t)384 * 768 * 2);
    float* zeros          = (float*)alloc(768 * 4);
    float* bf             = (float*)alloc(768 * 4);
    int* rs               = (int*)alloc((size_t)(GRIDN + 1) * 4);
    char* Ur              = alloc(szU);
    char* Vr              = alloc(szV);

    __hip_bfloat16* U  = (__hip_bfloat16*)Ur;
    __hip_bfloat16* V  = (__hip_bfloat16*)Vr;
    __hip_bfloat16* h1 = (__hip_bfloat16*)Ur;                 // dead before U

    hipMemsetAsync(zeros, 0, 768 * 4, stream);

    transpose_to_bf16<<<(384 * 384 + 255) / 256, 256, 0, stream>>>(w2, wt2, 384, 384, 0);
    transpose_to_bf16<<<(768 * 192 + 255) / 256, 256, 0, stream>>>(wm1, wtm1v, 192, 768, 576);
    transpose_to_bf16<<<(768 * 768 + 255) / 256, 256, 0, stream>>>(wm2, wtm2, 768, 768, 0);
    transpose_to_bf16<<<(768 * 384 + 255) / 256, 256, 0, stream>>>(wm3, wtm3, 768, 384, 0);
    fold_w3_wm1<<<(576 * 768 + 255) / 256, 256, 0, stream>>>(w3, wm1, wtm1f);
    fold_bias<<<3, 256, 0, stream>>>(b3, wm1, bm1, bf);
    calc_rowstart<<<(GRIDN + 1 + 255) / 256, 256, 0, stream>>>(edges, rs);

    if (ws_size >= NEED_FOLD) {
        // ========== FOLD PATH (r18 + fused m2-staging): no fuse_m1, no m1c traffic ==========
        const int CH = 32768;
        const int NCH = NEDGE / CH;
        char* S2r = alloc(szS2);                  // half-sums, cols [384,768)
        char* CA  = alloc(szM1);                  // meanM2 home (embeds overlay pre-loop)

        float* S2             = (float*)S2r;
        __hip_bfloat16* meshf2 = (__hip_bfloat16*)S2r;            // [h2|pe], spans S2+CA pre-loop
        __hip_bfloat16* gridf  = (__hip_bfloat16*)(S2r + szMesh);
        __hip_bfloat16* meanM2 = (__hip_bfloat16*)CA;

        embed_kernel<<<(NMESH * 96 + 255) / 256, 256, 0, stream>>>(mesh_pos, meshf2, NMESH, 576, 384);
        embed_kernel<<<(GRIDN * 96 + 255) / 256, 256, 0, stream>>>(grid_pos, gridf, GRIDN, 192, 0);

        lin1_kernel<<<(NMESH * HID + 255) / 256, 256, 0, stream>>>(x, w1, b1, h1);

        // meshf2[:, :384] = h2 = gelu(h1 @ w2 + b2)   (ldc=576)
        mfma_gemm<true, false, false><<<dim3(3, 391), 256, 0, stream>>>(
            h1, wt2, b2, meshf2, nullptr, NMESH, 384, 384, 576, nullptr, 0);
        // U = meshf2 @ Wfold + bf
        mfma_gemm<false, false, false><<<dim3(6, 391), 256, 0, stream>>>(
            meshf2, wtm1f, bf, U, nullptr, NMESH, 768, 576, 768, nullptr, 0);
        // V = gridf @ wm1[576:]
        mfma_gemm<false, false, false><<<dim3(6, 256), 256, 0, stream>>>(
            gridf, wtm1v, zeros, V, nullptr, GRIDN, 768, 192, 768, nullptr, 0);

        // embeds now dead: zero the split accumulator (d_out cols 0-383, S2 cols 384-767)
        hipMemsetAsync(out, 0, (size_t)GRIDN * 384 * 4, stream);
        hipMemsetAsync(S2, 0, (size_t)GRIDN * 384 * 4, stream);

        for (int c = 0; c < NCH; c++) {
            int e0 = c * CH;
            // split_sums[grid[e]] += gelu( gelu(U[mi]+V[gi]) @ wm2 + bm2 )  -- fully fused
            mfma_gemm_m2s<<<dim3(6, CH / 128), 256, 0, stream>>>(
                U, V, edges, e0, wtm2, bm2, out, S2);
        }

        mean_bf16<<<(GRIDN * 768 / 4 + 255) / 256, 256, 0, stream>>>(out, S2, rs, meanM2);
        // out = meanM2 @ wm3 + bm3   (f32, direct to d_out)
        mfma_gemm<false, true, false><<<dim3(3, 256), 256, 0, stream>>>(
            meanM2, wtm3, bm3, out, nullptr, GRIDN, 384, 768, 384, nullptr, 0);
        fix_empty<<<(GRIDN + 255) / 256, 256, 0, stream>>>(rs, out);
    } else {
        // ========== FALLBACK: r17's proven 128^2 path ==========
        const int CH = 32768;
        const int NCH = NEDGE / CH;
        char* CA = alloc(2 * rnd((size_t)CH * 768 * 2));

        __hip_bfloat16* meshf2 = (__hip_bfloat16*)CA;
        __hip_bfloat16* gridf  = (__hip_bfloat16*)(CA + szMesh);
        __hip_bfloat16* m1c    = (__hip_bfloat16*)CA;
        __hip_bfloat16* m2c    = (__hip_bfloat16*)(CA + rnd((size_t)CH * 768 * 2));
        __hip_bfloat16* m3c    = m1c;

        hipMemsetAsync(out, 0, (size_t)GRIDN * HID * 4, stream);

        embed_kernel<<<(NMESH * 96 + 255) / 256, 256, 0, stream>>>(mesh_pos, meshf2, NMESH, 576, 384);
        embed_kernel<<<(GRIDN * 96 + 255) / 256, 256, 0, stream>>>(grid_pos, gridf, GRIDN, 192, 0);

        lin1_kernel<<<(NMESH * HID + 255) / 256, 256, 0, stream>>>(x, w1, b1, h1);

        mfma_gemm<true, false, false><<<dim3(3, 391), 256, 0, stream>>>(
            h1, wt2, b2, meshf2, nullptr, NMESH, 384, 384, 576, nullptr, 0);
        mfma_gemm<false, false, false><<<dim3(6, 391), 256, 0, stream>>>(
            meshf2, wtm1f, bf, U, nullptr, NMESH, 768, 576, 768, nullptr, 0);
        mfma_gemm<false, false, false><<<dim3(6, 256), 256, 0, stream>>>(
            gridf, wtm1v, zeros, V, nullptr, GRIDN, 768, 192, 768, nullptr, 0);

        for (int c = 0; c < NCH; c++) {
            int e0 = c * CH;
            fuse_m1<<<(CH * 96 + 255) / 256, 256, 0, stream>>>(U, V, edges, e0, CH, m1c);
            mfma_gemm<true, false, false><<<dim3(6, CH / 128), 256, 0, stream>>>(
                m1c, wtm2, bm2, m2c, nullptr, CH, 768, 768, 768, nullptr, 0);
            mfma_gemm<false, false, false><<<dim3(3, CH / 128), 256, 0, stream>>>(
                m2c, wtm3, bm3, m3c, nullptr, CH, 384, 768, 384, nullptr, 0);
            seg_partial<<<GRIDN, 128, 0, stream>>>(edges, e0, e0 + CH, m3c, out);
        }

        seg_div<<<GRIDN, 128, 0, stream>>>(edges, out);
    }
}

// Round 21
// 1007.082 us; speedup vs baseline: 1.1809x; 1.0705x over previous
//
#include <hip/hip_runtime.h>
#include <hip/hip_bf16.h>

#define NMESH 50000
#define GRIDN 32768
#define NEDGE 131072
#define HID 384

using f32x4 = __attribute__((ext_vector_type(4))) float;
using bfrag = __attribute__((ext_vector_type(8))) short;
using i32x4 = __attribute__((ext_vector_type(4))) int;

__device__ __forceinline__ float gelu_f(float v) {
    return 0.5f * v * (1.0f + erff(v * 0.70710678118654752f));
}

__device__ __forceinline__ void load_lds16(const void* g, void* l) {
    __builtin_amdgcn_global_load_lds(
        (const __attribute__((address_space(1))) void*)g,
        (__attribute__((address_space(3))) void*)l,
        16, 0, 0);
}

// bijective XCD-chunking swizzle (m204)
__device__ __forceinline__ void xcd_swizzle(int& bx, int& by) {
    int gx = gridDim.x;
    int nwg = gx * gridDim.y;
    int l = blockIdx.y * gx + blockIdx.x;
    int q = nwg >> 3, r = nwg & 7;
    int xcd = l & 7, pos = l >> 3;
    int nl = (xcd < r ? xcd * (q + 1) : r * (q + 1) + (xcd - r) * q) + pos;
    by = nl / gx;
    bx = nl - by * gx;
}

// unpack 8+8 bf16, add f32, gelu, repack
__device__ __forceinline__ bfrag fuse8(i32x4 u, i32x4 v) {
    bfrag ub = *reinterpret_cast<bfrag*>(&u);
    bfrag vb = *reinterpret_cast<bfrag*>(&v);
    bfrag o;
    #pragma unroll
    for (int i = 0; i < 8; i++) {
        unsigned short us = (unsigned short)ub[i], vs = (unsigned short)vb[i];
        float a = __bfloat162float(*(__hip_bfloat16*)&us) + __bfloat162float(*(__hip_bfloat16*)&vs);
        a = gelu_f(a);
        __hip_bfloat16 hb = __float2bfloat16(a);
        o[i] = *(short*)&hb;
    }
    return o;
}

// ---------------- weight transpose + bf16 cast: wt[n*K+k] = w[(k0+k)*N+n] ----------------
__global__ void transpose_to_bf16(const float* __restrict__ w, __hip_bfloat16* __restrict__ wt,
                                  int K, int N, int k0) {
    int idx = blockIdx.x * blockDim.x + threadIdx.x;
    if (idx >= K * N) return;
    int n = idx / K;
    int k = idx - n * K;
    wt[idx] = __float2bfloat16(w[(size_t)(k0 + k) * N + n]);
}

// ---------------- fold w3 into wm1 ----------------
__global__ void fold_w3_wm1(const float* __restrict__ w3, const float* __restrict__ wm1,
                            __hip_bfloat16* __restrict__ wtf) {
    int idx = blockIdx.x * blockDim.x + threadIdx.x;
    if (idx >= 576 * 768) return;
    int k = idx / 768;
    int n = idx - k * 768;
    float acc;
    if (k < 384) {
        acc = 0.f;
        #pragma unroll 4
        for (int j = 0; j < 384; j++)
            acc = fmaf(w3[k * 384 + j], wm1[j * 768 + n], acc);
    } else {
        acc = wm1[(size_t)k * 768 + n];
    }
    wtf[(size_t)n * 576 + k] = __float2bfloat16(acc);
}

// ---------------- folded bias ----------------
__global__ void fold_bias(const float* __restrict__ b3, const float* __restrict__ wm1,
                          const float* __restrict__ bm1, float* __restrict__ bf) {
    int n = blockIdx.x * blockDim.x + threadIdx.x;
    if (n >= 768) return;
    float acc = bm1[n];
    #pragma unroll 4
    for (int k = 0; k < 384; k++) acc = fmaf(b3[k], wm1[(size_t)k * 768 + n], acc);
    bf[n] = acc;
}

// ---------------- rowstart[g] = lower_bound(edges[:,0], g) ----------------
__global__ void calc_rowstart(const int* __restrict__ edges, int* __restrict__ rs) {
    int g = blockIdx.x * blockDim.x + threadIdx.x;
    if (g > GRIDN) return;
    int l = 0, r = NEDGE;
    while (l < r) { int m = (l + r) >> 1; if (edges[2 * m] < g) l = m + 1; else r = m; }
    rs[g] = l;
}

// ---------------- sincos positional embedding ----------------
__global__ void embed_kernel(const float* __restrict__ pos, __hip_bfloat16* __restrict__ outp,
                             int n, int stride, int coloff) {
    int idx = blockIdx.x * blockDim.x + threadIdx.x;
    if (idx >= n * 96) return;
    int nn = idx / 96;
    int rr = idx - nn * 96;
    int d = rr >> 5;
    int k = rr & 31;
    float v = pos[nn * 3 + d];
    float omega = expf(-0.28782313662425575f * (float)k);  // ln(10000)/32
    float a = v * omega;
    __hip_bfloat16* o = outp + (size_t)nn * stride + coloff + d * 64 + k;
    o[0]  = __float2bfloat16(sinf(a));
    o[32] = __float2bfloat16(cosf(a));
}

// ---------------- layer 1 ----------------
__global__ void lin1_kernel(const float* __restrict__ x, const float* __restrict__ w,
                            const float* __restrict__ b, __hip_bfloat16* __restrict__ h1) {
    int idx = blockIdx.x * blockDim.x + threadIdx.x;
    if (idx >= NMESH * HID) return;
    int m = idx / HID;
    int n = idx - m * HID;
    float acc = b[n];
    const float* xr = x + m * 16;
    #pragma unroll
    for (int k = 0; k < 16; k++) acc = fmaf(xr[k], w[k * HID + n], acc);
    h1[idx] = __float2bfloat16(gelu_f(acc));
}

// ======================================================================
// 128x128-tile bf16 MFMA GEMM (proven body, 3-buffer counted-vmcnt,
// pre-swizzled global_load_lds, 0 bank conflicts / no spill measured).
// Epilogues: bf16 store / f32 store / SEGA = gelu + f32 atomicAdd into a
// SPLIT accumulator: cols<384 -> Cv (stride 384), cols>=384 -> Cv2.
// ======================================================================
template<bool GELU, bool F32OUT, bool SEGA>
__launch_bounds__(256, 3)
__global__ void mfma_gemm(const __hip_bfloat16* __restrict__ A,
                          const __hip_bfloat16* __restrict__ Wt,
                          const float* __restrict__ bias,
                          void* __restrict__ Cv, void* __restrict__ Cv2,
                          int M, int N, int K, int ldc,
                          const int* __restrict__ seg_edges, int seg_e0) {
    __shared__ __align__(16) __hip_bfloat16 As[3][4096];
    __shared__ __align__(16) __hip_bfloat16 Bs[3][4096];

    const int t = threadIdx.x;
    const int lane = t & 63;
    const int wave = t >> 6;
    const int wm0 = (wave >> 1) * 64;
    const int wn0 = (wave & 1) * 64;

    int bx, by;
    xcd_swizzle(bx, by);
    const int row0 = by * 128;
    const int col0 = bx * 128;

    const int rS0 = t >> 2;
    const int rS1 = rS0 + 64;
    const int kcS = (t & 3) ^ ((t >> 3) & 3);

    const __hip_bfloat16* aP0 = A + (size_t)min(row0 + rS0, M - 1) * K;
    const __hip_bfloat16* aP1 = A + (size_t)min(row0 + rS1, M - 1) * K;
    const __hip_bfloat16* bP0 = Wt + (size_t)(col0 + rS0) * K;
    const __hip_bfloat16* bP1 = Wt + (size_t)(col0 + rS1) * K;

    const int off0 = (wave * 64) * 16;
    const int off1 = (256 + wave * 64) * 16;

    f32x4 acc[4][4] = {};

    const int kq = lane >> 4;
    const int lr = lane & 15;
    const int kqx = kq ^ ((lr >> 1) & 3);
    const int rdA = (wm0 + lr) * 32 + kqx * 8;
    const int rdB = (wn0 + lr) * 32 + kqx * 8;

    const int nsteps = K >> 5;

    auto stage = [&](int ks, int buf) {
        int k = ks * 32 + kcS * 8;
        load_lds16(aP0 + k, (char*)As[buf] + off0);
        load_lds16(aP1 + k, (char*)As[buf] + off1);
        load_lds16(bP0 + k, (char*)Bs[buf] + off0);
        load_lds16(bP1 + k, (char*)Bs[buf] + off1);
    };

    stage(0, 0);
    stage(1, 1);

    int cur = 0;
    int stg = 2;
    for (int ks = 0; ks < nsteps; ks++) {
        if (ks + 1 < nsteps) {
            asm volatile("s_waitcnt vmcnt(4)" ::: "memory");
        } else {
            asm volatile("s_waitcnt vmcnt(0)" ::: "memory");
        }
        __builtin_amdgcn_s_barrier();
        if (ks + 2 < nsteps) stage(ks + 2, stg);

        bfrag aF[4], bF[4];
        #pragma unroll
        for (int i = 0; i < 4; i++) {
            aF[i] = *reinterpret_cast<const bfrag*>(&As[cur][rdA + i * 512]);
            bF[i] = *reinterpret_cast<const bfrag*>(&Bs[cur][rdB + i * 512]);
        }
        asm volatile("s_waitcnt lgkmcnt(0)" ::: "memory");
        __builtin_amdgcn_sched_barrier(0);
        __builtin_amdgcn_s_setprio(1);
        #pragma unroll
        for (int i = 0; i < 4; i++) {
            #pragma unroll
            for (int j = 0; j < 4; j++) {
                acc[i][j] = __builtin_amdgcn_mfma_f32_16x16x32_bf16(aF[i], bF[j], acc[i][j], 0, 0, 0);
            }
        }
        __builtin_amdgcn_s_setprio(0);

        cur = (cur == 2) ? 0 : cur + 1;
        stg = (stg == 2) ? 0 : stg + 1;
    }

    if constexpr (SEGA) {
        float* o0 = (float*)Cv;    // cols [0,384), row stride 384
        float* o1 = (float*)Cv2;   // cols [384,768), row stride 384
        #pragma unroll
        for (int i = 0; i < 4; i++) {
            int rbase = seg_e0 + row0 + wm0 + i * 16 + kq * 4;
            int g0 = seg_edges[2 * (rbase + 0)];
            int g1 = seg_edges[2 * (rbase + 1)];
            int g2 = seg_edges[2 * (rbase + 2)];
            int g3 = seg_edges[2 * (rbase + 3)];
            bool same = (g0 == g1) & (g1 == g2) & (g2 == g3);
            #pragma unroll
            for (int j = 0; j < 4; j++) {
                int col = col0 + wn0 + j * 16 + lr;
                float* base = (col < 384) ? (o0 + col) : (o1 + (col - 384));
                float v0 = gelu_f(acc[i][j][0] + bias[col]);
                float v1 = gelu_f(acc[i][j][1] + bias[col]);
                float v2 = gelu_f(acc[i][j][2] + bias[col]);
                float v3 = gelu_f(acc[i][j][3] + bias[col]);
                if (same) {
                    unsafeAtomicAdd(base + (size_t)g0 * 384, v0 + v1 + v2 + v3);
                } else {
                    unsafeAtomicAdd(base + (size_t)g0 * 384, v0);
                    unsafeAtomicAdd(base + (size_t)g1 * 384, v1);
                    unsafeAtomicAdd(base + (size_t)g2 * 384, v2);
                    unsafeAtomicAdd(base + (size_t)g3 * 384, v3);
                }
            }
        }
    } else {
        #pragma unroll
        for (int i = 0; i < 4; i++) {
            #pragma unroll
            for (int j = 0; j < 4; j++) {
                #pragma unroll
                for (int r = 0; r < 4; r++) {
                    int row = row0 + wm0 + i * 16 + kq * 4 + r;
                    int col = col0 + wn0 + j * 16 + lr;
                    if (row < M) {
                        float v = acc[i][j][r] + bias[col];
                        if constexpr (GELU) v = gelu_f(v);
                        if constexpr (F32OUT)
                            ((float*)Cv)[(size_t)row * ldc + col] = v;
                        else
                            ((__hip_bfloat16*)Cv)[(size_t)row * ldc + col] = __float2bfloat16(v);
                    }
                }
            }
        }
    }
}

// ---------------- m1 fuse: m1c[e] = gelu(U[mesh_idx[e]] + V[grid_idx[e]]) ----------------
__global__ void fuse_m1(const __hip_bfloat16* __restrict__ U, const __hip_bfloat16* __restrict__ V,
                        const int* __restrict__ edges, int e0, int ne,
                        __hip_bfloat16* __restrict__ m1c) {
    int idx = blockIdx.x * blockDim.x + threadIdx.x;
    if (idx >= ne * 96) return;
    int e = idx / 96;
    int c8 = (idx - e * 96) * 8;
    int ge = e0 + e;
    int mi = edges[2 * ge + 1];
    int gi = edges[2 * ge + 0];
    i32x4 u = *reinterpret_cast<const i32x4*>(U + (size_t)mi * 768 + c8);
    i32x4 v = *reinterpret_cast<const i32x4*>(V + (size_t)gi * 768 + c8);
    *reinterpret_cast<bfrag*>(m1c + (size_t)e * 768 + c8) = fuse8(u, v);
}

// ---------------- meanM2 = bf16(split_sums / max(cnt,1)) ----------------
__global__ void mean_bf16(const float* __restrict__ s0, const float* __restrict__ s1,
                          const int* __restrict__ rs, __hip_bfloat16* __restrict__ mm) {
    int idx = blockIdx.x * blockDim.x + threadIdx.x;
    int base = idx * 4;
    if (base >= GRIDN * 768) return;
    int g = base / 768;
    int c = base - g * 768;
    int cnt = rs[g + 1] - rs[g];
    float inv = 1.0f / (float)max(cnt, 1);
    float4 v = (c < 384) ? *reinterpret_cast<const float4*>(s0 + (size_t)g * 384 + c)
                         : *reinterpret_cast<const float4*>(s1 + (size_t)g * 384 + (c - 384));
    __hip_bfloat16 o[4] = {__float2bfloat16(v.x * inv), __float2bfloat16(v.y * inv),
                           __float2bfloat16(v.z * inv), __float2bfloat16(v.w * inv)};
    *reinterpret_cast<uint2*>(mm + base) = *reinterpret_cast<const uint2*>(o);
}

// ---------------- zero output rows of empty segments ----------------
__global__ void fix_empty(const int* __restrict__ rs, float* __restrict__ out) {
    int g = blockIdx.x * blockDim.x + threadIdx.x;
    if (g >= GRIDN || (rs[g + 1] - rs[g]) != 0) return;
    float* row = out + (size_t)g * HID;
    for (int c = 0; c < HID; c++) row[c] = 0.f;
}

// ---------------- fallback: 384-wide seg machinery (proven) ----------------
__global__ void seg_partial(const int* __restrict__ edges, int e0, int e1,
                            const __hip_bfloat16* __restrict__ m3c, float* __restrict__ out) {
    int g = blockIdx.x;
    int l = e0, r = e1;
    while (l < r) { int mid = (l + r) >> 1; if (edges[2 * mid] < g) l = mid + 1; else r = mid; }
    int lo = l;
    r = e1;
    while (l < r) { int mid = (l + r) >> 1; if (edges[2 * mid] <= g) l = mid + 1; else r = mid; }
    int hi = l;
    if (lo >= hi) return;
    int c = threadIdx.x;
    float s0 = 0.f, s1 = 0.f, s2 = 0.f;
    for (int e = lo; e < hi; e++) {
        const __hip_bfloat16* rp = m3c + (size_t)(e - e0) * HID;
        s0 += __bfloat162float(rp[c]);
        s1 += __bfloat162float(rp[c + 128]);
        s2 += __bfloat162float(rp[c + 256]);
    }
    float* orow = out + (size_t)g * HID;
    orow[c] += s0;
    orow[c + 128] += s1;
    orow[c + 256] += s2;
}

__global__ void seg_div(const int* __restrict__ edges, float* __restrict__ out) {
    int g = blockIdx.x;
    int l = 0, r = NEDGE;
    while (l < r) { int mid = (l + r) >> 1; if (edges[2 * mid] < g) l = mid + 1; else r = mid; }
    int lo = l;
    r = NEDGE;
    while (l < r) { int mid = (l + r) >> 1; if (edges[2 * mid] <= g) l = mid + 1; else r = mid; }
    int cnt = l - lo;
    float inv = 1.0f / (float)max(cnt, 1);
    int c = threadIdx.x;
    float* orow = out + (size_t)g * HID;
    orow[c] *= inv;
    orow[c + 128] *= inv;
    orow[c + 256] *= inv;
}

extern "C" void kernel_launch(void* const* d_in, const int* in_sizes, int n_in,
                              void* d_out, int out_size, void* d_ws, size_t ws_size,
                              hipStream_t stream) {
    const float* x        = (const float*)d_in[0];
    const float* mesh_pos = (const float*)d_in[1];
    const float* grid_pos = (const float*)d_in[2];
    const int*   edges    = (const int*)d_in[3];
    const float* w1  = (const float*)d_in[4];
    const float* b1  = (const float*)d_in[5];
    const float* w2  = (const float*)d_in[6];
    const float* b2  = (const float*)d_in[7];
    const float* w3  = (const float*)d_in[8];
    const float* b3  = (const float*)d_in[9];
    const float* wm1 = (const float*)d_in[10];
    const float* bm1 = (const float*)d_in[11];
    const float* wm2 = (const float*)d_in[12];
    const float* bm2 = (const float*)d_in[13];
    const float* wm3 = (const float*)d_in[14];
    const float* bm3 = (const float*)d_in[15];
    float* out = (float*)d_out;

    auto rnd = [](size_t b) { return (b + 255) & ~(size_t)255; };
    const size_t wbytes = rnd((size_t)384 * 384 * 2) + rnd((size_t)768 * 576 * 2) +
                          rnd((size_t)768 * 192 * 2) + rnd((size_t)768 * 768 * 2) +
                          rnd((size_t)384 * 768 * 2) + rnd(768 * 4) * 2 +
                          rnd((size_t)(GRIDN + 1) * 4);
    const size_t szU    = rnd((size_t)NMESH * 768 * 2);     // 76.8 MB
    const size_t szV    = rnd((size_t)GRIDN * 768 * 2);     // 50.33 MB
    const size_t szMesh = rnd((size_t)NMESH * 576 * 2);     // 57.6 MB
    const size_t szS2   = rnd((size_t)GRIDN * 384 * 4);     // 50.33 MB (half-sums)
    const size_t szM1   = rnd((size_t)32768 * 768 * 2);     // 50.33 MB

    // fold path: weights + U + V + S2 + m1c = ~231.2 MB (engaged in r18)
    const size_t NEED_FOLD = wbytes + szU + szV + szS2 + szM1;

    char* p = (char*)d_ws;
    auto alloc = [&](size_t b) { char* r = p; p += (b + 255) & ~(size_t)255; return r; };

    // common prep allocations
    __hip_bfloat16* wt2   = (__hip_bfloat16*)alloc((size_t)384 * 384 * 2);
    __hip_bfloat16* wtm1f = (__hip_bfloat16*)alloc((size_t)768 * 576 * 2);
    __hip_bfloat16* wtm1v = (__hip_bfloat16*)alloc((size_t)768 * 192 * 2);
    __hip_bfloat16* wtm2  = (__hip_bfloat16*)alloc((size_t)768 * 768 * 2);
    __hip_bfloat16* wtm3  = (__hip_bfloat16*)alloc((size_t)384 * 768 * 2);
    float* zeros          = (float*)alloc(768 * 4);
    float* bf             = (float*)alloc(768 * 4);
    int* rs               = (int*)alloc((size_t)(GRIDN + 1) * 4);
    char* Ur              = alloc(szU);
    char* Vr              = alloc(szV);

    __hip_bfloat16* U  = (__hip_bfloat16*)Ur;
    __hip_bfloat16* V  = (__hip_bfloat16*)Vr;
    __hip_bfloat16* h1 = (__hip_bfloat16*)Ur;                 // [0, 38.4 MB), dead before U

    hipMemsetAsync(zeros, 0, 768 * 4, stream);

    transpose_to_bf16<<<(384 * 384 + 255) / 256, 256, 0, stream>>>(w2, wt2, 384, 384, 0);
    transpose_to_bf16<<<(768 * 192 + 255) / 256, 256, 0, stream>>>(wm1, wtm1v, 192, 768, 576);
    transpose_to_bf16<<<(768 * 768 + 255) / 256, 256, 0, stream>>>(wm2, wtm2, 768, 768, 0);
    transpose_to_bf16<<<(768 * 384 + 255) / 256, 256, 0, stream>>>(wm3, wtm3, 768, 384, 0);
    fold_w3_wm1<<<(576 * 768 + 255) / 256, 256, 0, stream>>>(w3, wm1, wtm1f);
    fold_bias<<<3, 256, 0, stream>>>(b3, wm1, bm1, bf);
    calc_rowstart<<<(GRIDN + 1 + 255) / 256, 256, 0, stream>>>(edges, rs);

    if (ws_size >= NEED_FOLD) {
        // ========== FOLD PATH (231 MB): U/V + w3-fold + m3-fold w/ SPLIT atomic sums ==========
        const int CH = 32768;
        const int NCH = NEDGE / CH;
        char* S2r = alloc(szS2);                  // half-sums, cols [384,768)
        char* CA  = alloc(szM1);                  // m1c

        float* S2             = (float*)S2r;
        __hip_bfloat16* meshf2 = (__hip_bfloat16*)S2r;            // [h2|pe] 57.6MB spans S2+CA
        __hip_bfloat16* gridf  = (__hip_bfloat16*)(S2r + szMesh); // 12.6MB
        __hip_bfloat16* m1c    = (__hip_bfloat16*)CA;
        __hip_bfloat16* meanM2 = (__hip_bfloat16*)CA;             // reuse after loop (m1c dead)

        embed_kernel<<<(NMESH * 96 + 255) / 256, 256, 0, stream>>>(mesh_pos, meshf2, NMESH, 576, 384);
        embed_kernel<<<(GRIDN * 96 + 255) / 256, 256, 0, stream>>>(grid_pos, gridf, GRIDN, 192, 0);

        lin1_kernel<<<(NMESH * HID + 255) / 256, 256, 0, stream>>>(x, w1, b1, h1);

        // meshf2[:, :384] = h2 = gelu(h1 @ w2 + b2)   (ldc=576)
        mfma_gemm<true, false, false><<<dim3(3, 391), 256, 0, stream>>>(
            h1, wt2, b2, meshf2, nullptr, NMESH, 384, 384, 576, nullptr, 0);
        // U = meshf2 @ Wfold + bf
        mfma_gemm<false, false, false><<<dim3(6, 391), 256, 0, stream>>>(
            meshf2, wtm1f, bf, U, nullptr, NMESH, 768, 576, 768, nullptr, 0);
        // V = gridf @ wm1[576:]
        mfma_gemm<false, false, false><<<dim3(6, 256), 256, 0, stream>>>(
            gridf, wtm1v, zeros, V, nullptr, GRIDN, 768, 192, 768, nullptr, 0);

        // embeds now dead: zero the split accumulator (d_out = cols 0-383, S2 = cols 384-767)
        hipMemsetAsync(out, 0, (size_t)GRIDN * 384 * 4, stream);
        hipMemsetAsync(S2, 0, (size_t)GRIDN * 384 * 4, stream);

        for (int c = 0; c < NCH; c++) {
            int e0 = c * CH;
            fuse_m1<<<(CH * 96 + 255) / 256, 256, 0, stream>>>(U, V, edges, e0, CH, m1c);
            // split_sums[grid[e]] += gelu(m1c @ wm2 + bm2)   (atomic-seg epilogue)
            mfma_gemm<true, false, true><<<dim3(6, CH / 128), 256, 0, stream>>>(
                m1c, wtm2, bm2, out, S2, CH, 768, 768, 768, edges, e0);
        }

        mean_bf16<<<(GRIDN * 768 / 4 + 255) / 256, 256, 0, stream>>>(out, S2, rs, meanM2);
        // out = meanM2 @ wm3 + bm3   (f32, overwrites the accumulator half -- meanM2 extracted)
        mfma_gemm<false, true, false><<<dim3(3, 256), 256, 0, stream>>>(
            meanM2, wtm3, bm3, out, nullptr, GRIDN, 384, 768, 384, nullptr, 0);
        fix_empty<<<(GRIDN + 255) / 256, 256, 0, stream>>>(rs, out);
    } else {
        // ========== FALLBACK: proven 128^2 path (separate m2 + m3 + 384-wide seg) ==========
        const int CH = 32768;
        const int NCH = NEDGE / CH;
        char* CA = alloc(2 * rnd((size_t)CH * 768 * 2));

        __hip_bfloat16* meshf2 = (__hip_bfloat16*)CA;
        __hip_bfloat16* gridf  = (__hip_bfloat16*)(CA + szMesh);
        __hip_bfloat16* m1c    = (__hip_bfloat16*)CA;
        __hip_bfloat16* m2c    = (__hip_bfloat16*)(CA + rnd((size_t)CH * 768 * 2));
        __hip_bfloat16* m3c    = m1c;

        hipMemsetAsync(out, 0, (size_t)GRIDN * HID * 4, stream);

        embed_kernel<<<(NMESH * 96 + 255) / 256, 256, 0, stream>>>(mesh_pos, meshf2, NMESH, 576, 384);
        embed_kernel<<<(GRIDN * 96 + 255) / 256, 256, 0, stream>>>(grid_pos, gridf, GRIDN, 192, 0);

        lin1_kernel<<<(NMESH * HID + 255) / 256, 256, 0, stream>>>(x, w1, b1, h1);

        mfma_gemm<true, false, false><<<dim3(3, 391), 256, 0, stream>>>(
            h1, wt2, b2, meshf2, nullptr, NMESH, 384, 384, 576, nullptr, 0);
        mfma_gemm<false, false, false><<<dim3(6, 391), 256, 0, stream>>>(
            meshf2, wtm1f, bf, U, nullptr, NMESH, 768, 576, 768, nullptr, 0);
        mfma_gemm<false, false, false><<<dim3(6, 256), 256, 0, stream>>>(
            gridf, wtm1v, zeros, V, nullptr, GRIDN, 768, 192, 768, nullptr, 0);

        for (int c = 0; c < NCH; c++) {
            int e0 = c * CH;
            fuse_m1<<<(CH * 96 + 255) / 256, 256, 0, stream>>>(U, V, edges, e0, CH, m1c);
            mfma_gemm<true, false, false><<<dim3(6, CH / 128), 256, 0, stream>>>(
                m1c, wtm2, bm2, m2c, nullptr, CH, 768, 768, 768, nullptr, 0);
            mfma_gemm<false, false, false><<<dim3(3, CH / 128), 256, 0, stream>>>(
                m2c, wtm3, bm3, m3c, nullptr, CH, 384, 768, 384, nullptr, 0);
            seg_partial<<<GRIDN, 128, 0, stream>>>(edges, e0, e0 + CH, m3c, out);
        }

        seg_div<<<GRIDN, 128, 0, stream>>>(edges, out);
    }
}

// Round 22
// 875.010 us; speedup vs baseline: 1.3591x; 1.1509x over previous
//
#include <hip/hip_runtime.h>
#include <hip/hip_bf16.h>

#define NMESH 50000
#define GRIDN 32768
#define NEDGE 131072
#define HID 384

using f32x4 = __attribute__((ext_vector_type(4))) float;
using bfrag = __attribute__((ext_vector_type(8))) short;
using i32x4 = __attribute__((ext_vector_type(4))) int;

__device__ __forceinline__ float gelu_f(float v) {
    return 0.5f * v * (1.0f + erff(v * 0.70710678118654752f));
}

__device__ __forceinline__ void load_lds16(const void* g, void* l) {
    __builtin_amdgcn_global_load_lds(
        (const __attribute__((address_space(1))) void*)g,
        (__attribute__((address_space(3))) void*)l,
        16, 0, 0);
}

// bijective XCD-chunking swizzle (m204)
__device__ __forceinline__ void xcd_swizzle(int& bx, int& by) {
    int gx = gridDim.x;
    int nwg = gx * gridDim.y;
    int l = blockIdx.y * gx + blockIdx.x;
    int q = nwg >> 3, r = nwg & 7;
    int xcd = l & 7, pos = l >> 3;
    int nl = (xcd < r ? xcd * (q + 1) : r * (q + 1) + (xcd - r) * q) + pos;
    by = nl / gx;
    bx = nl - by * gx;
}

// unpack 8+8 bf16, add f32, gelu, repack
__device__ __forceinline__ bfrag fuse8(i32x4 u, i32x4 v) {
    bfrag ub = *reinterpret_cast<bfrag*>(&u);
    bfrag vb = *reinterpret_cast<bfrag*>(&v);
    bfrag o;
    #pragma unroll
    for (int i = 0; i < 8; i++) {
        unsigned short us = (unsigned short)ub[i], vs = (unsigned short)vb[i];
        float a = __bfloat162float(*(__hip_bfloat16*)&us) + __bfloat162float(*(__hip_bfloat16*)&vs);
        a = gelu_f(a);
        __hip_bfloat16 hb = __float2bfloat16(a);
        o[i] = *(short*)&hb;
    }
    return o;
}

// ---------------- weight transpose + bf16 cast: wt[n*K+k] = w[(k0+k)*N+n] ----------------
__global__ void transpose_to_bf16(const float* __restrict__ w, __hip_bfloat16* __restrict__ wt,
                                  int K, int N, int k0) {
    int idx = blockIdx.x * blockDim.x + threadIdx.x;
    if (idx >= K * N) return;
    int n = idx / K;
    int k = idx - n * K;
    wt[idx] = __float2bfloat16(w[(size_t)(k0 + k) * N + n]);
}

// ---------------- fold w3 into wm1 ----------------
__global__ void fold_w3_wm1(const float* __restrict__ w3, const float* __restrict__ wm1,
                            __hip_bfloat16* __restrict__ wtf) {
    int idx = blockIdx.x * blockDim.x + threadIdx.x;
    if (idx >= 576 * 768) return;
    int k = idx / 768;
    int n = idx - k * 768;
    float acc;
    if (k < 384) {
        acc = 0.f;
        #pragma unroll 4
        for (int j = 0; j < 384; j++)
            acc = fmaf(w3[k * 384 + j], wm1[j * 768 + n], acc);
    } else {
        acc = wm1[(size_t)k * 768 + n];
    }
    wtf[(size_t)n * 576 + k] = __float2bfloat16(acc);
}

// ---------------- folded bias ----------------
__global__ void fold_bias(const float* __restrict__ b3, const float* __restrict__ wm1,
                          const float* __restrict__ bm1, float* __restrict__ bf) {
    int n = blockIdx.x * blockDim.x + threadIdx.x;
    if (n >= 768) return;
    float acc = bm1[n];
    #pragma unroll 4
    for (int k = 0; k < 384; k++) acc = fmaf(b3[k], wm1[(size_t)k * 768 + n], acc);
    bf[n] = acc;
}

// ---------------- rowstart[g] = lower_bound(edges[:,0], g) ----------------
__global__ void calc_rowstart(const int* __restrict__ edges, int* __restrict__ rs) {
    int g = blockIdx.x * blockDim.x + threadIdx.x;
    if (g > GRIDN) return;
    int l = 0, r = NEDGE;
    while (l < r) { int m = (l + r) >> 1; if (edges[2 * m] < g) l = m + 1; else r = m; }
    rs[g] = l;
}

// ---------------- sincos positional embedding ----------------
__global__ void embed_kernel(const float* __restrict__ pos, __hip_bfloat16* __restrict__ outp,
                             int n, int stride, int coloff) {
    int idx = blockIdx.x * blockDim.x + threadIdx.x;
    if (idx >= n * 96) return;
    int nn = idx / 96;
    int rr = idx - nn * 96;
    int d = rr >> 5;
    int k = rr & 31;
    float v = pos[nn * 3 + d];
    float omega = expf(-0.28782313662425575f * (float)k);  // ln(10000)/32
    float a = v * omega;
    __hip_bfloat16* o = outp + (size_t)nn * stride + coloff + d * 64 + k;
    o[0]  = __float2bfloat16(sinf(a));
    o[32] = __float2bfloat16(cosf(a));
}

// ---------------- layer 1 ----------------
__global__ void lin1_kernel(const float* __restrict__ x, const float* __restrict__ w,
                            const float* __restrict__ b, __hip_bfloat16* __restrict__ h1) {
    int idx = blockIdx.x * blockDim.x + threadIdx.x;
    if (idx >= NMESH * HID) return;
    int m = idx / HID;
    int n = idx - m * HID;
    float acc = b[n];
    const float* xr = x + m * 16;
    #pragma unroll
    for (int k = 0; k < 16; k++) acc = fmaf(xr[k], w[k * HID + n], acc);
    h1[idx] = __float2bfloat16(gelu_f(acc));
}

// ======================================================================
// 128x128-tile bf16 MFMA GEMM (proven body, 3-buffer counted-vmcnt,
// pre-swizzled global_load_lds, 0 bank conflicts / no spill measured).
// Epilogues:
//   bf16 / f32 store (unchanged), or
//   SEGA: per-CELL LDS pre-reduction -- block writes its post-gelu
//   128x128 tile to LDS (bf16, [128][132] padded), then one f32 atomic
//   per (cell,col) instead of per (edge,col): ~4x atomic-traffic cut.
//   Rows-per-cell from rowstart[] clamped to the block's edge range.
// ======================================================================
template<bool GELU, bool F32OUT, bool SEGA>
__launch_bounds__(256, 3)
__global__ void mfma_gemm(const __hip_bfloat16* __restrict__ A,
                          const __hip_bfloat16* __restrict__ Wt,
                          const float* __restrict__ bias,
                          void* __restrict__ Cv, void* __restrict__ Cv2,
                          int M, int N, int K, int ldc,
                          const int* __restrict__ seg_edges,
                          const int* __restrict__ seg_rs, int seg_e0) {
    // unified 48KB LDS: A-buffers [0,12288) elems, B-buffers [12288,24576) elems.
    // SEGA epilogue reuses it as P[128][132] bf16 (16896 elems).
    __shared__ __align__(16) __hip_bfloat16 ldsraw[24576];
    __hip_bfloat16* AsB = ldsraw;              // 3 buffers x 4096 elems
    __hip_bfloat16* BsB = ldsraw + 12288;      // 3 buffers x 4096 elems

    const int t = threadIdx.x;
    const int lane = t & 63;
    const int wave = t >> 6;
    const int wm0 = (wave >> 1) * 64;
    const int wn0 = (wave & 1) * 64;

    int bx, by;
    xcd_swizzle(bx, by);
    const int row0 = by * 128;
    const int col0 = bx * 128;

    const int rS0 = t >> 2;
    const int rS1 = rS0 + 64;
    const int kcS = (t & 3) ^ ((t >> 3) & 3);

    const __hip_bfloat16* aP0 = A + (size_t)min(row0 + rS0, M - 1) * K;
    const __hip_bfloat16* aP1 = A + (size_t)min(row0 + rS1, M - 1) * K;
    const __hip_bfloat16* bP0 = Wt + (size_t)(col0 + rS0) * K;
    const __hip_bfloat16* bP1 = Wt + (size_t)(col0 + rS1) * K;

    const int off0 = (wave * 64) * 16;          // byte offset within a buffer
    const int off1 = (256 + wave * 64) * 16;

    f32x4 acc[4][4] = {};

    const int kq = lane >> 4;
    const int lr = lane & 15;
    const int kqx = kq ^ ((lr >> 1) & 3);
    const int rdA = (wm0 + lr) * 32 + kqx * 8;
    const int rdB = (wn0 + lr) * 32 + kqx * 8;

    const int nsteps = K >> 5;

    auto stage = [&](int ks, int buf) {
        int k = ks * 32 + kcS * 8;
        load_lds16(aP0 + k, (char*)AsB + buf * 8192 + off0);
        load_lds16(aP1 + k, (char*)AsB + buf * 8192 + off1);
        load_lds16(bP0 + k, (char*)BsB + buf * 8192 + off0);
        load_lds16(bP1 + k, (char*)BsB + buf * 8192 + off1);
    };

    stage(0, 0);
    stage(1, 1);

    int cur = 0;
    int stg = 2;
    for (int ks = 0; ks < nsteps; ks++) {
        if (ks + 1 < nsteps) {
            asm volatile("s_waitcnt vmcnt(4)" ::: "memory");
        } else {
            asm volatile("s_waitcnt vmcnt(0)" ::: "memory");
        }
        __builtin_amdgcn_s_barrier();
        if (ks + 2 < nsteps) stage(ks + 2, stg);

        bfrag aF[4], bF[4];
        #pragma unroll
        for (int i = 0; i < 4; i++) {
            aF[i] = *reinterpret_cast<const bfrag*>(&AsB[cur * 4096 + rdA + i * 512]);
            bF[i] = *reinterpret_cast<const bfrag*>(&BsB[cur * 4096 + rdB + i * 512]);
        }
        asm volatile("s_waitcnt lgkmcnt(0)" ::: "memory");
        __builtin_amdgcn_sched_barrier(0);
        __builtin_amdgcn_s_setprio(1);
        #pragma unroll
        for (int i = 0; i < 4; i++) {
            #pragma unroll
            for (int j = 0; j < 4; j++) {
                acc[i][j] = __builtin_amdgcn_mfma_f32_16x16x32_bf16(aF[i], bF[j], acc[i][j], 0, 0, 0);
            }
        }
        __builtin_amdgcn_s_setprio(0);

        cur = (cur == 2) ? 0 : cur + 1;
        stg = (stg == 2) ? 0 : stg + 1;
    }

    if constexpr (SEGA) {
        // ---- per-cell LDS pre-reduction (M is a multiple of 128 on this path) ----
        float* o0 = (float*)Cv;    // cols [0,384), row stride 384
        float* o1 = (float*)Cv2;   // cols [384,768), row stride 384

        __syncthreads();           // all waves done with K-loop LDS reads
        // write post-gelu tile to LDS: P[row][col], padded stride 132
        #pragma unroll
        for (int i = 0; i < 4; i++) {
            #pragma unroll
            for (int j = 0; j < 4; j++) {
                #pragma unroll
                for (int r = 0; r < 4; r++) {
                    int rowL = wm0 + i * 16 + kq * 4 + r;
                    int colL = wn0 + j * 16 + lr;
                    ldsraw[rowL * 132 + colL] =
                        __float2bfloat16(gelu_f(acc[i][j][r] + bias[col0 + colL]));
                }
            }
        }
        __syncthreads();

        // block's edge range: [eb, eb+128)
        const int eb = seg_e0 + row0;
        const int gf = seg_edges[2 * eb];            // first cell in block
        const int gl = seg_edges[2 * (eb + 127)];    // last cell in block
        const int ncells = gl - gf + 1;
        const int ntask = ncells * 128;

        for (int task = t; task < ntask; task += 256) {
            int cell = gf + (task >> 7);
            int colL = task & 127;
            int lo = max(seg_rs[cell] - eb, 0);
            int hi = min(seg_rs[cell + 1] - eb, 128);
            if (lo >= hi) continue;
            float s = 0.f;
            for (int rw = lo; rw < hi; rw++)
                s += __bfloat162float(ldsraw[rw * 132 + colL]);
            int col = col0 + colL;
            float* base = (col < 384) ? (o0 + col) : (o1 + (col - 384));
            unsafeAtomicAdd(base + (size_t)cell * 384, s);
        }
    } else {
        #pragma unroll
        for (int i = 0; i < 4; i++) {
            #pragma unroll
            for (int j = 0; j < 4; j++) {
                #pragma unroll
                for (int r = 0; r < 4; r++) {
                    int row = row0 + wm0 + i * 16 + kq * 4 + r;
                    int col = col0 + wn0 + j * 16 + lr;
                    if (row < M) {
                        float v = acc[i][j][r] + bias[col];
                        if constexpr (GELU) v = gelu_f(v);
                        if constexpr (F32OUT)
                            ((float*)Cv)[(size_t)row * ldc + col] = v;
                        else
                            ((__hip_bfloat16*)Cv)[(size_t)row * ldc + col] = __float2bfloat16(v);
                    }
                }
            }
        }
    }
}

// ---------------- m1 fuse: m1c[e] = gelu(U[mesh_idx[e]] + V[grid_idx[e]]) ----------------
__global__ void fuse_m1(const __hip_bfloat16* __restrict__ U, const __hip_bfloat16* __restrict__ V,
                        const int* __restrict__ edges, int e0, int ne,
                        __hip_bfloat16* __restrict__ m1c) {
    int idx = blockIdx.x * blockDim.x + threadIdx.x;
    if (idx >= ne * 96) return;
    int e = idx / 96;
    int c8 = (idx - e * 96) * 8;
    int ge = e0 + e;
    int mi = edges[2 * ge + 1];
    int gi = edges[2 * ge + 0];
    i32x4 u = *reinterpret_cast<const i32x4*>(U + (size_t)mi * 768 + c8);
    i32x4 v = *reinterpret_cast<const i32x4*>(V + (size_t)gi * 768 + c8);
    *reinterpret_cast<bfrag*>(m1c + (size_t)e * 768 + c8) = fuse8(u, v);
}

// ---------------- meanM2 = bf16(split_sums / max(cnt,1)) ----------------
__global__ void mean_bf16(const float* __restrict__ s0, const float* __restrict__ s1,
                          const int* __restrict__ rs, __hip_bfloat16* __restrict__ mm) {
    int idx = blockIdx.x * blockDim.x + threadIdx.x;
    int base = idx * 4;
    if (base >= GRIDN * 768) return;
    int g = base / 768;
    int c = base - g * 768;
    int cnt = rs[g + 1] - rs[g];
    float inv = 1.0f / (float)max(cnt, 1);
    float4 v = (c < 384) ? *reinterpret_cast<const float4*>(s0 + (size_t)g * 384 + c)
                         : *reinterpret_cast<const float4*>(s1 + (size_t)g * 384 + (c - 384));
    __hip_bfloat16 o[4] = {__float2bfloat16(v.x * inv), __float2bfloat16(v.y * inv),
                           __float2bfloat16(v.z * inv), __float2bfloat16(v.w * inv)};
    *reinterpret_cast<uint2*>(mm + base) = *reinterpret_cast<const uint2*>(o);
}

// ---------------- zero output rows of empty segments ----------------
__global__ void fix_empty(const int* __restrict__ rs, float* __restrict__ out) {
    int g = blockIdx.x * blockDim.x + threadIdx.x;
    if (g >= GRIDN || (rs[g + 1] - rs[g]) != 0) return;
    float* row = out + (size_t)g * HID;
    for (int c = 0; c < HID; c++) row[c] = 0.f;
}

// ---------------- fallback: 384-wide seg machinery (proven) ----------------
__global__ void seg_partial(const int* __restrict__ edges, int e0, int e1,
                            const __hip_bfloat16* __restrict__ m3c, float* __restrict__ out) {
    int g = blockIdx.x;
    int l = e0, r = e1;
    while (l < r) { int mid = (l + r) >> 1; if (edges[2 * mid] < g) l = mid + 1; else r = mid; }
    int lo = l;
    r = e1;
    while (l < r) { int mid = (l + r) >> 1; if (edges[2 * mid] <= g) l = mid + 1; else r = mid; }
    int hi = l;
    if (lo >= hi) return;
    int c = threadIdx.x;
    float s0 = 0.f, s1 = 0.f, s2 = 0.f;
    for (int e = lo; e < hi; e++) {
        const __hip_bfloat16* rp = m3c + (size_t)(e - e0) * HID;
        s0 += __bfloat162float(rp[c]);
        s1 += __bfloat162float(rp[c + 128]);
        s2 += __bfloat162float(rp[c + 256]);
    }
    float* orow = out + (size_t)g * HID;
    orow[c] += s0;
    orow[c + 128] += s1;
    orow[c + 256] += s2;
}

__global__ void seg_div(const int* __restrict__ edges, float* __restrict__ out) {
    int g = blockIdx.x;
    int l = 0, r = NEDGE;
    while (l < r) { int mid = (l + r) >> 1; if (edges[2 * mid] < g) l = mid + 1; else r = mid; }
    int lo = l;
    r = NEDGE;
    while (l < r) { int mid = (l + r) >> 1; if (edges[2 * mid] <= g) l = mid + 1; else r = mid; }
    int cnt = l - lo;
    float inv = 1.0f / (float)max(cnt, 1);
    int c = threadIdx.x;
    float* orow = out + (size_t)g * HID;
    orow[c] *= inv;
    orow[c + 128] *= inv;
    orow[c + 256] *= inv;
}

extern "C" void kernel_launch(void* const* d_in, const int* in_sizes, int n_in,
                              void* d_out, int out_size, void* d_ws, size_t ws_size,
                              hipStream_t stream) {
    const float* x        = (const float*)d_in[0];
    const float* mesh_pos = (const float*)d_in[1];
    const float* grid_pos = (const float*)d_in[2];
    const int*   edges    = (const int*)d_in[3];
    const float* w1  = (const float*)d_in[4];
    const float* b1  = (const float*)d_in[5];
    const float* w2  = (const float*)d_in[6];
    const float* b2  = (const float*)d_in[7];
    const float* w3  = (const float*)d_in[8];
    const float* b3  = (const float*)d_in[9];
    const float* wm1 = (const float*)d_in[10];
    const float* bm1 = (const float*)d_in[11];
    const float* wm2 = (const float*)d_in[12];
    const float* bm2 = (const float*)d_in[13];
    const float* wm3 = (const float*)d_in[14];
    const float* bm3 = (const float*)d_in[15];
    float* out = (float*)d_out;

    auto rnd = [](size_t b) { return (b + 255) & ~(size_t)255; };
    const size_t wbytes = rnd((size_t)384 * 384 * 2) + rnd((size_t)768 * 576 * 2) +
                          rnd((size_t)768 * 192 * 2) + rnd((size_t)768 * 768 * 2) +
                          rnd((size_t)384 * 768 * 2) + rnd(768 * 4) * 2 +
                          rnd((size_t)(GRIDN + 1) * 4);
    const size_t szU    = rnd((size_t)NMESH * 768 * 2);     // 76.8 MB
    const size_t szV    = rnd((size_t)GRIDN * 768 * 2);     // 50.33 MB
    const size_t szMesh = rnd((size_t)NMESH * 576 * 2);     // 57.6 MB
    const size_t szS2   = rnd((size_t)GRIDN * 384 * 4);     // 50.33 MB (half-sums)
    const size_t szM1   = rnd((size_t)32768 * 768 * 2);     // 50.33 MB

    // fold path: weights + U + V + S2 + m1c = ~231.2 MB (engaged r18/r21)
    const size_t NEED_FOLD = wbytes + szU + szV + szS2 + szM1;

    char* p = (char*)d_ws;
    auto alloc = [&](size_t b) { char* r = p; p += (b + 255) & ~(size_t)255; return r; };

    // common prep allocations
    __hip_bfloat16* wt2   = (__hip_bfloat16*)alloc((size_t)384 * 384 * 2);
    __hip_bfloat16* wtm1f = (__hip_bfloat16*)alloc((size_t)768 * 576 * 2);
    __hip_bfloat16* wtm1v = (__hip_bfloat16*)alloc((size_t)768 * 192 * 2);
    __hip_bfloat16* wtm2  = (__hip_bfloat16*)alloc((size_t)768 * 768 * 2);
    __hip_bfloat16* wtm3  = (__hip_bfloat16*)alloc((size_t)384 * 768 * 2);
    float* zeros          = (float*)alloc(768 * 4);
    float* bf             = (float*)alloc(768 * 4);
    int* rs               = (int*)alloc((size_t)(GRIDN + 1) * 4);
    char* Ur              = alloc(szU);
    char* Vr              = alloc(szV);

    __hip_bfloat16* U  = (__hip_bfloat16*)Ur;
    __hip_bfloat16* V  = (__hip_bfloat16*)Vr;
    __hip_bfloat16* h1 = (__hip_bfloat16*)Ur;                 // [0, 38.4 MB), dead before U

    hipMemsetAsync(zeros, 0, 768 * 4, stream);

    transpose_to_bf16<<<(384 * 384 + 255) / 256, 256, 0, stream>>>(w2, wt2, 384, 384, 0);
    transpose_to_bf16<<<(768 * 192 + 255) / 256, 256, 0, stream>>>(wm1, wtm1v, 192, 768, 576);
    transpose_to_bf16<<<(768 * 768 + 255) / 256, 256, 0, stream>>>(wm2, wtm2, 768, 768, 0);
    transpose_to_bf16<<<(768 * 384 + 255) / 256, 256, 0, stream>>>(wm3, wtm3, 768, 384, 0);
    fold_w3_wm1<<<(576 * 768 + 255) / 256, 256, 0, stream>>>(w3, wm1, wtm1f);
    fold_bias<<<3, 256, 0, stream>>>(b3, wm1, bm1, bf);
    calc_rowstart<<<(GRIDN + 1 + 255) / 256, 256, 0, stream>>>(edges, rs);

    if (ws_size >= NEED_FOLD) {
        // ========== FOLD PATH (231 MB): U/V + w3-fold + m3-fold w/ per-cell atomic sums ==========
        const int CH = 32768;
        const int NCH = NEDGE / CH;
        char* S2r = alloc(szS2);                  // half-sums, cols [384,768)
        char* CA  = alloc(szM1);                  // m1c

        float* S2             = (float*)S2r;
        __hip_bfloat16* meshf2 = (__hip_bfloat16*)S2r;            // [h2|pe] spans S2+CA pre-loop
        __hip_bfloat16* gridf  = (__hip_bfloat16*)(S2r + szMesh);
        __hip_bfloat16* m1c    = (__hip_bfloat16*)CA;
        __hip_bfloat16* meanM2 = (__hip_bfloat16*)CA;             // reuse after loop (m1c dead)

        embed_kernel<<<(NMESH * 96 + 255) / 256, 256, 0, stream>>>(mesh_pos, meshf2, NMESH, 576, 384);
        embed_kernel<<<(GRIDN * 96 + 255) / 256, 256, 0, stream>>>(grid_pos, gridf, GRIDN, 192, 0);

        lin1_kernel<<<(NMESH * HID + 255) / 256, 256, 0, stream>>>(x, w1, b1, h1);

        // meshf2[:, :384] = h2 = gelu(h1 @ w2 + b2)   (ldc=576)
        mfma_gemm<true, false, false><<<dim3(3, 391), 256, 0, stream>>>(
            h1, wt2, b2, meshf2, nullptr, NMESH, 384, 384, 576, nullptr, nullptr, 0);
        // U = meshf2 @ Wfold + bf
        mfma_gemm<false, false, false><<<dim3(6, 391), 256, 0, stream>>>(
            meshf2, wtm1f, bf, U, nullptr, NMESH, 768, 576, 768, nullptr, nullptr, 0);
        // V = gridf @ wm1[576:]
        mfma_gemm<false, false, false><<<dim3(6, 256), 256, 0, stream>>>(
            gridf, wtm1v, zeros, V, nullptr, GRIDN, 768, 192, 768, nullptr, nullptr, 0);

        // embeds now dead: zero the split accumulator (d_out = cols 0-383, S2 = cols 384-767)
        hipMemsetAsync(out, 0, (size_t)GRIDN * 384 * 4, stream);
        hipMemsetAsync(S2, 0, (size_t)GRIDN * 384 * 4, stream);

        for (int c = 0; c < NCH; c++) {
            int e0 = c * CH;
            fuse_m1<<<(CH * 96 + 255) / 256, 256, 0, stream>>>(U, V, edges, e0, CH, m1c);
            // split_sums[cell] += sum_rows gelu(m1c @ wm2 + bm2)  (per-cell LDS-reduced atomics)
            mfma_gemm<true, false, true><<<dim3(6, CH / 128), 256, 0, stream>>>(
                m1c, wtm2, bm2, out, S2, CH, 768, 768, 768, edges, rs, e0);
        }

        mean_bf16<<<(GRIDN * 768 / 4 + 255) / 256, 256, 0, stream>>>(out, S2, rs, meanM2);
        // out = meanM2 @ wm3 + bm3   (f32, overwrites the accumulator half)
        mfma_gemm<false, true, false><<<dim3(3, 256), 256, 0, stream>>>(
            meanM2, wtm3, bm3, out, nullptr, GRIDN, 384, 768, 384, nullptr, nullptr, 0);
        fix_empty<<<(GRIDN + 255) / 256, 256, 0, stream>>>(rs, out);
    } else {
        // ========== FALLBACK: proven 128^2 path (separate m2 + m3 + 384-wide seg) ==========
        const int CH = 32768;
        const int NCH = NEDGE / CH;
        char* CA = alloc(2 * rnd((size_t)CH * 768 * 2));

        __hip_bfloat16* meshf2 = (__hip_bfloat16*)CA;
        __hip_bfloat16* gridf  = (__hip_bfloat16*)(CA + szMesh);
        __hip_bfloat16* m1c    = (__hip_bfloat16*)CA;
        __hip_bfloat16* m2c    = (__hip_bfloat16*)(CA + rnd((size_t)CH * 768 * 2));
        __hip_bfloat16* m3c    = m1c;

        hipMemsetAsync(out, 0, (size_t)GRIDN * HID * 4, stream);

        embed_kernel<<<(NMESH * 96 + 255) / 256, 256, 0, stream>>>(mesh_pos, meshf2, NMESH, 576, 384);
        embed_kernel<<<(GRIDN * 96 + 255) / 256, 256, 0, stream>>>(grid_pos, gridf, GRIDN, 192, 0);

        lin1_kernel<<<(NMESH * HID + 255) / 256, 256, 0, stream>>>(x, w1, b1, h1);

        mfma_gemm<true, false, false><<<dim3(3, 391), 256, 0, stream>>>(
            h1, wt2, b2, meshf2, nullptr, NMESH, 384, 384, 576, nullptr, nullptr, 0);
        mfma_gemm<false, false, false><<<dim3(6, 391), 256, 0, stream>>>(
            meshf2, wtm1f, bf, U, nullptr, NMESH, 768, 576, 768, nullptr, nullptr, 0);
        mfma_gemm<false, false, false><<<dim3(6, 256), 256, 0, stream>>>(
            gridf, wtm1v, zeros, V, nullptr, GRIDN, 768, 192, 768, nullptr, nullptr, 0);

        for (int c = 0; c < NCH; c++) {
            int e0 = c * CH;
            fuse_m1<<<(CH * 96 + 255) / 256, 256, 0, stream>>>(U, V, edges, e0, CH, m1c);
            mfma_gemm<true, false, false><<<dim3(6, CH / 128), 256, 0, stream>>>(
                m1c, wtm2, bm2, m2c, nullptr, CH, 768, 768, 768, nullptr, nullptr, 0);
            mfma_gemm<false, false, false><<<dim3(3, CH / 128), 256, 0, stream>>>(
                m2c, wtm3, bm3, m3c, nullptr, CH, 384, 768, 384, nullptr, nullptr, 0);
            seg_partial<<<GRIDN, 128, 0, stream>>>(edges, e0, e0 + CH, m3c, out);
        }

        seg_div<<<GRIDN, 128, 0, stream>>>(edges, out);
    }
}